// Round 5
// baseline (2287.015 us; speedup 1.0000x reference)
//
#include <hip/hip_runtime.h>
#include <math.h>

#define BB 4
#define UU 512
#define DD 80
#define HH 8
#define FFND 2048
#define LL 12
#define SEGC 32
#define LCC 50
#define RCC 8
#define NSEG 16
#define RCL 128
#define KK 640
#define ROWS (BB*KK)        // 2560
#define OUTD 768
#define NBLK 256
#define EPSF 1e-5f
#define SCALEF 0.31622776601683794f  // (D/H)^-0.5

typedef __attribute__((ext_vector_type(8))) short bf16x8;
typedef __attribute__((ext_vector_type(4))) float f32x4;

__device__ inline unsigned short f2bf(float f) {
  unsigned int u = __float_as_uint(f);
  u += 0x7fffu + ((u >> 16) & 1u);
  return (unsigned short)(u >> 16);
}

struct Prm {
  const float *mel, *lng, *lnb, *Wq, *bq, *Wkv, *bkv, *Wo, *bo;
  const float *ffg, *ffb, *W1, *b1, *W2, *b2, *og, *ob, *Wp, *bp;
  const int* lens;
  float *out, *x, *qkv, *attn, *res;
  unsigned short *ffln, *w1bf, *w2bf;
  unsigned int* bar;
};

// software grid barrier: monotone counter, release/acquire via __threadfence.
// Correct for any k-th barrier: counter must reach k*NBLK. No reset needed
// within a run; init kernel zeroes it each iteration (workspace is poisoned).
__device__ inline void gsync(unsigned int* bar, int tid) {
  __syncthreads();
  if (tid == 0) {
    __threadfence();                       // release: my writes visible
    unsigned my = atomicAdd(bar, 1u) + 1u;
    unsigned goal = ((my + NBLK - 1u) / NBLK) * NBLK;
    while (atomicAdd(bar, 0u) < goal) __builtin_amdgcn_s_sleep(4);
    __threadfence();                       // acquire: invalidate stale caches
  }
  __syncthreads();
}

__global__ void k_init(unsigned int* bar) {
  if (threadIdx.x == 0) *bar = 0u;
}

// One persistent kernel. 256 blocks x 256 threads (>=2 blocks/CU capacity at
// 56832B LDS -> all 256 co-resident; software barrier cannot deadlock).
__global__ __launch_bounds__(256, 1) void k_all(Prm p) {
  __shared__ __align__(16) char smraw[56832];
  const int tid = threadIdx.x;
  const int bid = blockIdx.x;

  // ---------------- phase 0: gather + weight cvt ----------------
  for (int idx = bid * 256 + tid; idx < ROWS * DD; idx += NBLK * 256) {
    int d = idx % DD, row = idx / DD, b = row / KK, j = row % KK;
    int pos;
    if (j < RCL) {
      int i = j >> 3, r = j & 7;
      pos = (i < NSEG - 1) ? (i + 1) * SEGC + r : UU + r;
    } else {
      pos = j - RCL;
    }
    p.x[idx] = p.mel[(b * (UU + RCC) + pos) * DD + d];
  }
  const int NV = (LL * FFND * DD) / 4;
  for (int t = bid * 256 + tid; t < 2 * NV; t += NBLK * 256) {
    const float* src; unsigned short* dst; int i2;
    if (t < NV) { src = p.W1; dst = p.w1bf; i2 = t; }
    else        { src = p.W2; dst = p.w2bf; i2 = t - NV; }
    float4 v = reinterpret_cast<const float4*>(src)[i2];
    ushort4 r;
    r.x = f2bf(v.x); r.y = f2bf(v.y); r.z = f2bf(v.z); r.w = f2bf(v.w);
    reinterpret_cast<ushort4*>(dst)[i2] = r;
  }
  gsync(p.bar, tid);

  for (int l = 0; l < LL; ++l) {
    const float* lWq  = p.Wq  + l * DD * DD;
    const float* lbq  = p.bq  + l * DD;
    const float* lWkv = p.Wkv + l * 2 * DD * DD;
    const float* lbkv = p.bkv + l * 2 * DD;
    const float* lWo  = p.Wo  + l * DD * DD;
    const float* lbo  = p.bo  + l * DD;
    const float* lng_ = p.lng + l * DD;
    const float* lnb_ = p.lnb + l * DD;
    const float* ffg_ = p.ffg + l * DD;
    const float* ffb_ = p.ffb + l * DD;
    const unsigned short* W1l = p.w1bf + l * FFND * DD;
    const float* b1l = p.b1 + l * FFND;
    const unsigned short* W2l = p.w2bf + l * FFND * DD;
    const float* b2l = p.b2 + l * DD;
    const float* ogl = p.og + l * DD;
    const float* obl = p.ob + l * DD;

    // ---------------- QKV: LN_in + GEMM, 240 units ----------------
    for (int u = bid; u < 240; u += NBLK) {
      float* s_x  = (float*)smraw;               // 32*84
      float* s_w  = (float*)(smraw + 10752);     // 80*84
      float* s_mu = (float*)(smraw + 37632);     // 32
      float* s_ri = (float*)(smraw + 37760);     // 32
      int r0 = (u % 80) * 32;
      int ct = u / 80;
      __syncthreads();
      for (int k = 0; k < 3; ++k) {
        int idx = tid + k * 256;
        if (idx < 640) {
          int row = idx / 20, c4 = idx % 20;
          *reinterpret_cast<float4*>(&s_x[row * 84 + c4 * 4]) =
              *reinterpret_cast<const float4*>(&p.x[(r0 + row) * DD + c4 * 4]);
        }
      }
      const float* Wbase = (ct == 0) ? lWq : (ct == 1 ? lWkv : (lWkv + 80 * DD));
      for (int k = 0; k < 7; ++k) {
        int idx = tid + k * 256;
        if (idx < 1600) {
          int c = idx / 20, d4 = idx % 20;
          *reinterpret_cast<float4*>(&s_w[c * 84 + d4 * 4]) =
              *reinterpret_cast<const float4*>(&Wbase[c * DD + d4 * 4]);
        }
      }
      __syncthreads();
      {
        int rr = tid >> 3, t8 = tid & 7;
        float sm = 0.f, sq = 0.f;
        for (int d = t8 * 10; d < t8 * 10 + 10; ++d) {
          float v = s_x[rr * 84 + d];
          sm += v; sq += v * v;
        }
        for (int m = 4; m >= 1; m >>= 1) {
          sm += __shfl_xor(sm, m, 8);
          sq += __shfl_xor(sq, m, 8);
        }
        if (t8 == 0) {
          float mu = sm * (1.f / DD);
          s_mu[rr] = mu;
          s_ri[rr] = rsqrtf(sq * (1.f / DD) - mu * mu + EPSF);
        }
      }
      __syncthreads();
      for (int k = 0; k < 10; ++k) {
        int e = tid + k * 256;
        int row = e / 80, d = e % 80;
        s_x[row * 84 + d] = (s_x[row * 84 + d] - s_mu[row]) * s_ri[row] * lng_[d] + lnb_[d];
      }
      __syncthreads();
      int ty = tid >> 4, tx = tid & 15;
      float acc[2][5] = {};
      for (int d4 = 0; d4 < 20; ++d4) {
        float4 a0 = *reinterpret_cast<const float4*>(&s_x[(2 * ty) * 84 + d4 * 4]);
        float4 a1 = *reinterpret_cast<const float4*>(&s_x[(2 * ty + 1) * 84 + d4 * 4]);
#pragma unroll
        for (int j = 0; j < 5; ++j) {
          float4 w = *reinterpret_cast<const float4*>(&s_w[(tx + 16 * j) * 84 + d4 * 4]);
          acc[0][j] += a0.x * w.x + a0.y * w.y + a0.z * w.z + a0.w * w.w;
          acc[1][j] += a1.x * w.x + a1.y * w.y + a1.z * w.z + a1.w * w.w;
        }
      }
      const float* bias = (ct == 0) ? lbq : (lbkv + (ct == 2 ? 80 : 0));
      for (int i2 = 0; i2 < 2; ++i2)
        for (int j = 0; j < 5; ++j) {
          int c = tx + 16 * j;
          int grow = r0 + 2 * ty + i2;
          p.qkv[grow * 240 + ct * 80 + c] = acc[i2][j] + bias[c];
        }
    }
    gsync(p.bar, tid);

    // ---------------- ATTN: 512 units (i,h,b) ----------------
    for (int u = bid; u < 512; u += NBLK) {
      float* s_k   = (float*)smraw;              // 900
      float* s_v   = (float*)(smraw + 3600);     // 900
      float* s_q   = (float*)(smraw + 7200);     // 400
      float* s_p   = (float*)(smraw + 8800);     // 3600
      float* s_kb  = (float*)(smraw + 23200);    // 90
      float* s_den = (float*)(smraw + 23560);    // 40
      int i = u & 15, h = (u >> 4) & 7, b = u >> 7;
      int s = i * SEGC - LCC; if (s < 0) s = 0;
      int e = (i + 1) * SEGC;
      int nk = RCC + (e - s);  // <= 90
      int len = p.lens[b];
      __syncthreads();
      if (tid < 90 && tid < nk) {
        int j = tid;
        int kr = (j < RCC) ? i * RCC + j : RCL + s + (j - RCC);
        const float* kp = &p.qkv[(b * KK + kr) * 240 + 80 + h * 10];
        const float* vp = &p.qkv[(b * KK + kr) * 240 + 160 + h * 10];
#pragma unroll
        for (int d = 0; d < 10; ++d) { s_k[j * 10 + d] = kp[d]; s_v[j * 10 + d] = vp[d]; }
        s_kb[j] = (kr >= len + RCL) ? -1e8f : 0.f;
      }
      if (tid >= 128 && tid < 168) {
        int j = tid - 128;
        int qr = (j < RCC) ? i * RCC + j : RCL + i * SEGC + (j - RCC);
        const float* qp = &p.qkv[(b * KK + qr) * 240 + h * 10];
#pragma unroll
        for (int d = 0; d < 10; ++d) s_q[j * 10 + d] = qp[d];
      }
      __syncthreads();
      for (int pp = tid; pp < 3600; pp += 256) {
        int q = pp / 90, jk = pp % 90;
        float sc = -1e30f;
        if (jk < nk) {
          float dot = 0.f;
#pragma unroll
          for (int d = 0; d < 10; ++d) dot += s_q[q * 10 + d] * s_k[jk * 10 + d];
          sc = dot * SCALEF + s_kb[jk];
        }
        s_p[pp] = sc;
      }
      __syncthreads();
      if (tid < 160) {
        int r = tid >> 2, l4 = tid & 3;
        float m = -1e30f;
        for (int kx = l4; kx < 90; kx += 4) m = fmaxf(m, s_p[r * 90 + kx]);
        m = fmaxf(m, __shfl_xor(m, 1, 4));
        m = fmaxf(m, __shfl_xor(m, 2, 4));
        float sum = 0.f;
        for (int kx = l4; kx < 90; kx += 4) {
          float ev = __expf(s_p[r * 90 + kx] - m);
          s_p[r * 90 + kx] = ev;
          sum += ev;
        }
        sum += __shfl_xor(sum, 1, 4);
        sum += __shfl_xor(sum, 2, 4);
        if (l4 == 0) s_den[r] = sum;
      }
      __syncthreads();
      for (int po = tid; po < 400; po += 256) {
        int q = po / 10, d = po % 10;
        float o = 0.f;
        for (int kx = 0; kx < 90; ++kx) o += s_p[q * 90 + kx] * s_v[kx * 10 + d];
        int qr = (q < RCC) ? i * RCC + q : RCL + i * SEGC + (q - RCC);
        p.attn[(b * KK + qr) * DD + h * 10 + d] = o / s_den[q];
      }
    }
    gsync(p.bar, tid);

    // ---------------- OPROJ + residual + LN_ff: 160 units ----------------
    for (int u = bid; u < 160; u += NBLK) {
      float* s_at = (float*)smraw;               // 16*84
      float* s_x2 = (float*)(smraw + 5376);      // 16*84
      float* s_wo = (float*)(smraw + 10752);     // 80*84
      int r0 = u * 16;
      __syncthreads();
      for (int k = 0; k < 2; ++k) {
        int idx = tid + k * 256;
        if (idx < 320) {
          int row = idx / 20, c4 = idx % 20;
          *reinterpret_cast<float4*>(&s_at[row * 84 + c4 * 4]) =
              *reinterpret_cast<const float4*>(&p.attn[(r0 + row) * DD + c4 * 4]);
          *reinterpret_cast<float4*>(&s_x2[row * 84 + c4 * 4]) =
              *reinterpret_cast<const float4*>(&p.x[(r0 + row) * DD + c4 * 4]);
        }
      }
      for (int k = 0; k < 7; ++k) {
        int idx = tid + k * 256;
        if (idx < 1600) {
          int c = idx / 20, d4 = idx % 20;
          *reinterpret_cast<float4*>(&s_wo[c * 84 + d4 * 4]) =
              *reinterpret_cast<const float4*>(&lWo[c * DD + d4 * 4]);
        }
      }
      __syncthreads();
      int r = tid >> 4, tx = tid & 15;
      float acc[5] = {};
      for (int d4 = 0; d4 < 20; ++d4) {
        float4 a = *reinterpret_cast<const float4*>(&s_at[r * 84 + d4 * 4]);
#pragma unroll
        for (int j = 0; j < 5; ++j) {
          float4 w = *reinterpret_cast<const float4*>(&s_wo[(tx + 16 * j) * 84 + d4 * 4]);
          acc[j] += a.x * w.x + a.y * w.y + a.z * w.z + a.w * w.w;
        }
      }
      float val[5];
      float sm = 0.f, sq = 0.f;
#pragma unroll
      for (int j = 0; j < 5; ++j) {
        int c = tx + 16 * j;
        float v = acc[j] + lbo[c] + s_x2[r * 84 + c];
        val[j] = v;
        p.res[(r0 + r) * DD + c] = v;
        sm += v; sq += v * v;
      }
      for (int m = 8; m >= 1; m >>= 1) {
        sm += __shfl_xor(sm, m, 16);
        sq += __shfl_xor(sq, m, 16);
      }
      float mu = sm * (1.f / DD);
      float ri = rsqrtf(sq * (1.f / DD) - mu * mu + EPSF);
#pragma unroll
      for (int j = 0; j < 5; ++j) {
        int c = tx + 16 * j;
        p.ffln[(r0 + r) * DD + c] = f2bf((val[j] - mu) * ri * ffg_[c] + ffb_[c]);
      }
    }
    gsync(p.bar, tid);

    // ------- FFN full-K: 256 units x 10 rows; reg-prefetch staging -------
    // + b2 + residual + LN_out fused epilogue -> writes x
    {
      unsigned short* s_fa = (unsigned short*)smraw;            // 16*104
      unsigned short* s_w1 = (unsigned short*)(smraw + 3328);   // 128*104
      unsigned short* s_w2 = (unsigned short*)(smraw + 29952);  // 80*136
      unsigned short* s_h  = (unsigned short*)(smraw + 51712);  // 4*16*40
      float* s_red = (float*)(smraw + 3328);    // 16*80*4 per wave (alias s_w1)
      float* s_val = (float*)(smraw + 23808);   // 800 (alias s_w1 tail)
      float* s_mu2 = (float*)(smraw + 27008);   // 16
      float* s_ri2 = (float*)(smraw + 27072);   // 16
      int r0 = bid * 10;
      int w = tid >> 6, lane = tid & 63, m = lane & 15, q = lane >> 4;
      unsigned short* s_hw = s_h + w * (16 * 40);  // wave-private h slice
      __syncthreads();
      // stage A tile (10 rows; zero-pad rows 10..15 and cols 80..103)
      if (tid < 208) {
        int row = tid / 13, ch = tid % 13;
        uint4 v = make_uint4(0, 0, 0, 0);
        if (row < 10 && ch < 10)
          v = *reinterpret_cast<const uint4*>(&p.ffln[(r0 + row) * DD + ch * 8]);
        *reinterpret_cast<uint4*>(&s_fa[row * 104 + ch * 8]) = v;
      }
      {  // zero K-pad cols 80..95 of s_w1 (staging never writes them)
        int row = tid >> 1, half = tid & 1;
        uint4 z = make_uint4(0, 0, 0, 0);
        *reinterpret_cast<uint4*>(&s_w1[row * 104 + 80 + half * 8]) = z;
      }
      uint4 rw1[5], rw2[5];
#pragma unroll
      for (int k = 0; k < 5; ++k) {  // prefetch chunk 0
        int idx = tid + k * 256;
        int row1 = idx / 10, ch1 = idx % 10;
        rw1[k] = *reinterpret_cast<const uint4*>(&W1l[row1 * DD + ch1 * 8]);
      }
#pragma unroll
      for (int k = 0; k < 5; ++k) {
        int idx = tid + k * 256;
        int row2 = idx >> 4, ch2 = idx & 15;
        rw2[k] = *reinterpret_cast<const uint4*>(&W2l[row2 * FFND + ch2 * 8]);
      }
      f32x4 acc2[5] = {};
      for (int c = 0; c < 16; ++c) {
        int fc0 = c * 128;
        __syncthreads();  // prior chunk MFMA reads done (first: A/pad visible)
#pragma unroll
        for (int k = 0; k < 5; ++k) {
          int idx = tid + k * 256;
          int row1 = idx / 10, ch1 = idx % 10;
          *reinterpret_cast<uint4*>(&s_w1[row1 * 104 + ch1 * 8]) = rw1[k];
        }
#pragma unroll
        for (int k = 0; k < 5; ++k) {
          int idx = tid + k * 256;
          int row2 = idx >> 4, ch2 = idx & 15;
          *reinterpret_cast<uint4*>(&s_w2[row2 * 136 + ch2 * 8]) = rw2[k];
        }
        __syncthreads();
        if (c < 15) {  // issue next chunk loads; latency hides under MFMA
          int fn = fc0 + 128;
#pragma unroll
          for (int k = 0; k < 5; ++k) {
            int idx = tid + k * 256;
            int row1 = idx / 10, ch1 = idx % 10;
            rw1[k] = *reinterpret_cast<const uint4*>(&W1l[(fn + row1) * DD + ch1 * 8]);
          }
#pragma unroll
          for (int k = 0; k < 5; ++k) {
            int idx = tid + k * 256;
            int row2 = idx >> 4, ch2 = idx & 15;
            rw2[k] = *reinterpret_cast<const uint4*>(&W2l[row2 * FFND + fn + ch2 * 8]);
          }
        }
        // FFN1: wave w owns ffn cols [w*32, w*32+32) of this chunk
        f32x4 acc1[2] = {};
#pragma unroll
        for (int kk = 0; kk < 3; ++kk) {
          bf16x8 a = *reinterpret_cast<const bf16x8*>(&s_fa[m * 104 + kk * 32 + q * 8]);
#pragma unroll
          for (int ct2 = 0; ct2 < 2; ++ct2) {
            bf16x8 b = *reinterpret_cast<const bf16x8*>(
                &s_w1[(w * 32 + ct2 * 16 + m) * 104 + kk * 32 + q * 8]);
            acc1[ct2] = __builtin_amdgcn_mfma_f32_16x16x32_bf16(a, b, acc1[ct2], 0, 0, 0);
          }
        }
#pragma unroll
        for (int ct2 = 0; ct2 < 2; ++ct2) {
          float bias = b1l[fc0 + w * 32 + ct2 * 16 + m];
#pragma unroll
          for (int r = 0; r < 4; ++r)
            s_hw[(q * 4 + r) * 40 + ct2 * 16 + m] = f2bf(fmaxf(acc1[ct2][r] + bias, 0.f));
        }
        // FFN2 over this wave's 32-wide k-slice (wave-private s_h rows)
        bf16x8 a2 = *reinterpret_cast<const bf16x8*>(&s_hw[m * 40 + q * 8]);
#pragma unroll
        for (int ct = 0; ct < 5; ++ct) {
          bf16x8 b = *reinterpret_cast<const bf16x8*>(
              &s_w2[(ct * 16 + m) * 136 + w * 32 + q * 8]);
          acc2[ct] = __builtin_amdgcn_mfma_f32_16x16x32_bf16(a2, b, acc2[ct], 0, 0, 0);
        }
      }
      __syncthreads();  // all MFMA reads of s_w1 done; s_red may overwrite
#pragma unroll
      for (int ct = 0; ct < 5; ++ct)
#pragma unroll
        for (int r = 0; r < 4; ++r)
          s_red[w * 1280 + (q * 4 + r) * 80 + ct * 16 + m] = acc2[ct][r];
      __syncthreads();
      for (int e = tid; e < 800; e += 256) {
        int row = e / 80, cc = e % 80;
        float v = s_red[row * 80 + cc] + s_red[1280 + row * 80 + cc] +
                  s_red[2560 + row * 80 + cc] + s_red[3840 + row * 80 + cc];
        v += b2l[cc] + p.res[(r0 + row) * DD + cc];
        s_val[e] = v;
      }
      __syncthreads();
      if (tid < 80) {
        int rr = tid >> 3, t8 = tid & 7;
        float sm = 0.f, sq = 0.f;
        for (int d = t8 * 10; d < t8 * 10 + 10; ++d) {
          float v = s_val[rr * 80 + d];
          sm += v; sq += v * v;
        }
        for (int mm = 4; mm >= 1; mm >>= 1) {
          sm += __shfl_xor(sm, mm, 8);
          sq += __shfl_xor(sq, mm, 8);
        }
        if (t8 == 0) {
          float mu = sm * (1.f / DD);
          s_mu2[rr] = mu;
          s_ri2[rr] = rsqrtf(sq * (1.f / DD) - mu * mu + EPSF);
        }
      }
      __syncthreads();
      for (int e = tid; e < 800; e += 256) {
        int row = e / 80, cc = e % 80;
        p.x[(r0 + row) * DD + cc] =
            (s_val[e] - s_mu2[row]) * s_ri2[row] * ogl[cc] + obl[cc];
      }
    }
    gsync(p.bar, tid);
  }

  // ---------------- final projection: 384 units ----------------
  for (int u = bid; u < 384; u += NBLK) {
    float* s_pa = (float*)smraw;               // 64*84
    float* s_pw = (float*)(smraw + 21504);     // 64*84
    int gr0 = (u & 31) * 64;
    int c0 = (u >> 5) * 64;
    int b = gr0 / UU;
    int u0 = gr0 % UU;
    __syncthreads();
    for (int k = 0; k < 5; ++k) {
      int idx = tid + k * 256;
      int row = idx / 20, c4 = idx % 20;
      *reinterpret_cast<float4*>(&s_pa[row * 84 + c4 * 4]) =
          *reinterpret_cast<const float4*>(&p.x[(b * KK + RCL + u0 + row) * DD + c4 * 4]);
      *reinterpret_cast<float4*>(&s_pw[row * 84 + c4 * 4]) =
          *reinterpret_cast<const float4*>(&p.Wp[(c0 + row) * DD + c4 * 4]);
    }
    __syncthreads();
    int ty = tid >> 4, tx = tid & 15;
    float acc[4][4] = {};
    for (int d4 = 0; d4 < 20; ++d4) {
      float4 a[4], w[4];
#pragma unroll
      for (int i2 = 0; i2 < 4; ++i2)
        a[i2] = *reinterpret_cast<const float4*>(&s_pa[(4 * ty + i2) * 84 + d4 * 4]);
#pragma unroll
      for (int j = 0; j < 4; ++j)
        w[j] = *reinterpret_cast<const float4*>(&s_pw[(tx + 16 * j) * 84 + d4 * 4]);
#pragma unroll
      for (int i2 = 0; i2 < 4; ++i2)
#pragma unroll
        for (int j = 0; j < 4; ++j)
          acc[i2][j] += a[i2].x * w[j].x + a[i2].y * w[j].y +
                        a[i2].z * w[j].z + a[i2].w * w[j].w;
    }
    for (int i2 = 0; i2 < 4; ++i2)
      for (int j = 0; j < 4; ++j) {
        int c = c0 + tx + 16 * j;
        p.out[(gr0 + 4 * ty + i2) * OUTD + c] = acc[i2][j] + p.bp[c];
      }
  }
  if (bid == 0 && tid < BB)
    p.out[BB * UU * OUTD + tid] = (float)p.lens[tid];
}

extern "C" void kernel_launch(void* const* d_in, const int* in_sizes, int n_in,
                              void* d_out, int out_size, void* d_ws, size_t ws_size,
                              hipStream_t stream) {
  Prm p;
  p.mel = (const float*)d_in[0];
  p.lng = (const float*)d_in[1];
  p.lnb = (const float*)d_in[2];
  p.Wq  = (const float*)d_in[3];
  p.bq  = (const float*)d_in[4];
  p.Wkv = (const float*)d_in[5];
  p.bkv = (const float*)d_in[6];
  p.Wo  = (const float*)d_in[7];
  p.bo  = (const float*)d_in[8];
  p.ffg = (const float*)d_in[9];
  p.ffb = (const float*)d_in[10];
  p.W1  = (const float*)d_in[11];
  p.b1  = (const float*)d_in[12];
  p.W2  = (const float*)d_in[13];
  p.b2  = (const float*)d_in[14];
  p.og  = (const float*)d_in[15];
  p.ob  = (const float*)d_in[16];
  p.Wp  = (const float*)d_in[17];
  p.bp  = (const float*)d_in[18];
  p.lens = (const int*)d_in[19];
  p.out = (float*)d_out;

  float* ws = (float*)d_ws;
  p.x    = ws;                       // ROWS*DD
  p.qkv  = p.x + ROWS * DD;          // ROWS*240
  p.attn = p.qkv + ROWS * 240;       // ROWS*DD
  p.res  = p.attn + ROWS * DD;       // ROWS*DD
  p.ffln = (unsigned short*)(p.res + ROWS * DD);   // ROWS*DD bf16
  p.w1bf = p.ffln + ROWS * DD;                     // LL*FFND*DD bf16
  p.w2bf = p.w1bf + LL * FFND * DD;                // LL*FFND*DD bf16
  p.bar  = (unsigned int*)((char*)d_ws + (64u << 20));  // far past used region

  k_init<<<1, 64, 0, stream>>>(p.bar);
  k_all<<<NBLK, 256, 0, stream>>>(p);
}

// Round 6
// 2170.569 us; speedup vs baseline: 1.0536x; 1.0536x over previous
//
#include <hip/hip_runtime.h>
#include <math.h>

#define BB 4
#define UU 512
#define DD 80
#define HH 8
#define FFND 2048
#define LL 12
#define SEGC 32
#define LCC 50
#define RCC 8
#define NSEG 16
#define RCL 128
#define KK 640
#define ROWS (BB*KK)        // 2560
#define OUTD 768
#define NBLK 256
#define EPSF 1e-5f
#define SCALEF 0.31622776601683794f  // (D/H)^-0.5

typedef __attribute__((ext_vector_type(8))) short bf16x8;
typedef __attribute__((ext_vector_type(4))) float f32x4;

__device__ inline unsigned short f2bf(float f) {
  unsigned int u = __float_as_uint(f);
  u += 0x7fffu + ((u >> 16) & 1u);
  return (unsigned short)(u >> 16);
}

struct Prm {
  const float *mel, *lng, *lnb, *Wq, *bq, *Wkv, *bkv, *Wo, *bo;
  const float *ffg, *ffb, *W1, *b1, *W2, *b2, *og, *ob, *Wp, *bp;
  const int* lens;
  float *out, *x, *qkv, *attn;
  unsigned short *w1bf, *w2bf;
  unsigned int* bar;
};

// software grid barrier: monotone counter. Arrival = one RMW per block;
// waiting = device-scope atomic LOADS (concurrent, no line bouncing) with
// s_sleep backoff. threadfence pair gives release/acquire (L2 wb/inv).
__device__ inline void gsync(unsigned int* bar, int tid) {
  __syncthreads();
  if (tid == 0) {
    __threadfence();  // release: my writes visible device-wide
    unsigned my = __hip_atomic_fetch_add(bar, 1u, __ATOMIC_ACQ_REL,
                                         __HIP_MEMORY_SCOPE_AGENT) + 1u;
    unsigned goal = ((my + NBLK - 1u) / NBLK) * NBLK;
    while (__hip_atomic_load(bar, __ATOMIC_ACQUIRE,
                             __HIP_MEMORY_SCOPE_AGENT) < goal)
      __builtin_amdgcn_s_sleep(16);
    __threadfence();  // acquire: invalidate stale caches
  }
  __syncthreads();
}

__global__ void k_init(unsigned int* bar) {
  if (threadIdx.x == 0) *bar = 0u;
}

// One persistent kernel. 256 blocks x 256 threads, 1 block/CU (60032B LDS).
__global__ __launch_bounds__(256, 1) void k_all(Prm p) {
  __shared__ __align__(16) char smraw[60032];
  const int tid = threadIdx.x;
  const int bid = blockIdx.x;

  // ---------------- phase 0: gather + weight cvt ----------------
  for (int idx = bid * 256 + tid; idx < ROWS * DD; idx += NBLK * 256) {
    int d = idx % DD, row = idx / DD, b = row / KK, j = row % KK;
    int pos;
    if (j < RCL) {
      int i = j >> 3, r = j & 7;
      pos = (i < NSEG - 1) ? (i + 1) * SEGC + r : UU + r;
    } else {
      pos = j - RCL;
    }
    p.x[idx] = p.mel[(b * (UU + RCC) + pos) * DD + d];
  }
  const int NV = (LL * FFND * DD) / 4;
  for (int t = bid * 256 + tid; t < 2 * NV; t += NBLK * 256) {
    const float* src; unsigned short* dst; int i2;
    if (t < NV) { src = p.W1; dst = p.w1bf; i2 = t; }
    else        { src = p.W2; dst = p.w2bf; i2 = t - NV; }
    float4 v = reinterpret_cast<const float4*>(src)[i2];
    ushort4 r;
    r.x = f2bf(v.x); r.y = f2bf(v.y); r.z = f2bf(v.z); r.w = f2bf(v.w);
    reinterpret_cast<ushort4*>(dst)[i2] = r;
  }
  gsync(p.bar, tid);

  for (int l = 0; l < LL; ++l) {
    const float* lWq  = p.Wq  + l * DD * DD;
    const float* lbq  = p.bq  + l * DD;
    const float* lWkv = p.Wkv + l * 2 * DD * DD;
    const float* lbkv = p.bkv + l * 2 * DD;
    const float* lWo  = p.Wo  + l * DD * DD;
    const float* lbo  = p.bo  + l * DD;
    const float* lng_ = p.lng + l * DD;
    const float* lnb_ = p.lnb + l * DD;
    const float* ffg_ = p.ffg + l * DD;
    const float* ffb_ = p.ffb + l * DD;
    const unsigned short* W1l = p.w1bf + l * FFND * DD;
    const float* b1l = p.b1 + l * FFND;
    const unsigned short* W2l = p.w2bf + l * FFND * DD;
    const float* b2l = p.b2 + l * DD;
    const float* ogl = p.og + l * DD;
    const float* obl = p.ob + l * DD;

    // ---------------- QKV: LN_in + GEMM, 240 units ----------------
    for (int u = bid; u < 240; u += NBLK) {
      float* s_x  = (float*)smraw;               // 32*84
      float* s_w  = (float*)(smraw + 10752);     // 80*84
      float* s_mu = (float*)(smraw + 37632);     // 32
      float* s_ri = (float*)(smraw + 37760);     // 32
      int r0 = (u % 80) * 32;
      int ct = u / 80;
      __syncthreads();
      for (int k = 0; k < 3; ++k) {
        int idx = tid + k * 256;
        if (idx < 640) {
          int row = idx / 20, c4 = idx % 20;
          *reinterpret_cast<float4*>(&s_x[row * 84 + c4 * 4]) =
              *reinterpret_cast<const float4*>(&p.x[(r0 + row) * DD + c4 * 4]);
        }
      }
      const float* Wbase = (ct == 0) ? lWq : (ct == 1 ? lWkv : (lWkv + 80 * DD));
      for (int k = 0; k < 7; ++k) {
        int idx = tid + k * 256;
        if (idx < 1600) {
          int c = idx / 20, d4 = idx % 20;
          *reinterpret_cast<float4*>(&s_w[c * 84 + d4 * 4]) =
              *reinterpret_cast<const float4*>(&Wbase[c * DD + d4 * 4]);
        }
      }
      __syncthreads();
      {
        int rr = tid >> 3, t8 = tid & 7;
        float sm = 0.f, sq = 0.f;
        for (int d = t8 * 10; d < t8 * 10 + 10; ++d) {
          float v = s_x[rr * 84 + d];
          sm += v; sq += v * v;
        }
        for (int mm = 4; mm >= 1; mm >>= 1) {
          sm += __shfl_xor(sm, mm, 8);
          sq += __shfl_xor(sq, mm, 8);
        }
        if (t8 == 0) {
          float mu = sm * (1.f / DD);
          s_mu[rr] = mu;
          s_ri[rr] = rsqrtf(sq * (1.f / DD) - mu * mu + EPSF);
        }
      }
      __syncthreads();
      for (int k = 0; k < 10; ++k) {
        int e = tid + k * 256;
        int row = e / 80, d = e % 80;
        s_x[row * 84 + d] = (s_x[row * 84 + d] - s_mu[row]) * s_ri[row] * lng_[d] + lnb_[d];
      }
      __syncthreads();
      int ty = tid >> 4, tx = tid & 15;
      float acc[2][5] = {};
      for (int d4 = 0; d4 < 20; ++d4) {
        float4 a0 = *reinterpret_cast<const float4*>(&s_x[(2 * ty) * 84 + d4 * 4]);
        float4 a1 = *reinterpret_cast<const float4*>(&s_x[(2 * ty + 1) * 84 + d4 * 4]);
#pragma unroll
        for (int j = 0; j < 5; ++j) {
          float4 w = *reinterpret_cast<const float4*>(&s_w[(tx + 16 * j) * 84 + d4 * 4]);
          acc[0][j] += a0.x * w.x + a0.y * w.y + a0.z * w.z + a0.w * w.w;
          acc[1][j] += a1.x * w.x + a1.y * w.y + a1.z * w.z + a1.w * w.w;
        }
      }
      const float* bias = (ct == 0) ? lbq : (lbkv + (ct == 2 ? 80 : 0));
      for (int i2 = 0; i2 < 2; ++i2)
        for (int j = 0; j < 5; ++j) {
          int c = tx + 16 * j;
          int grow = r0 + 2 * ty + i2;
          p.qkv[grow * 240 + ct * 80 + c] = acc[i2][j] + bias[c];
        }
    }
    gsync(p.bar, tid);

    // ---------------- ATTN: 512 units (i,h,b) ----------------
    for (int u = bid; u < 512; u += NBLK) {
      float* s_k   = (float*)smraw;              // 900
      float* s_v   = (float*)(smraw + 3600);     // 900
      float* s_q   = (float*)(smraw + 7200);     // 400
      float* s_p   = (float*)(smraw + 8800);     // 3600
      float* s_kb  = (float*)(smraw + 23200);    // 90
      float* s_den = (float*)(smraw + 23560);    // 40
      int i = u & 15, h = (u >> 4) & 7, b = u >> 7;
      int s = i * SEGC - LCC; if (s < 0) s = 0;
      int e = (i + 1) * SEGC;
      int nk = RCC + (e - s);  // <= 90
      int len = p.lens[b];
      __syncthreads();
      if (tid < 90 && tid < nk) {
        int j = tid;
        int kr = (j < RCC) ? i * RCC + j : RCL + s + (j - RCC);
        const float* kp = &p.qkv[(b * KK + kr) * 240 + 80 + h * 10];
        const float* vp = &p.qkv[(b * KK + kr) * 240 + 160 + h * 10];
#pragma unroll
        for (int d = 0; d < 10; ++d) { s_k[j * 10 + d] = kp[d]; s_v[j * 10 + d] = vp[d]; }
        s_kb[j] = (kr >= len + RCL) ? -1e8f : 0.f;
      }
      if (tid >= 128 && tid < 168) {
        int j = tid - 128;
        int qr = (j < RCC) ? i * RCC + j : RCL + i * SEGC + (j - RCC);
        const float* qp = &p.qkv[(b * KK + qr) * 240 + h * 10];
#pragma unroll
        for (int d = 0; d < 10; ++d) s_q[j * 10 + d] = qp[d];
      }
      __syncthreads();
      for (int pp = tid; pp < 3600; pp += 256) {
        int q = pp / 90, jk = pp % 90;
        float sc = -1e30f;
        if (jk < nk) {
          float dot = 0.f;
#pragma unroll
          for (int d = 0; d < 10; ++d) dot += s_q[q * 10 + d] * s_k[jk * 10 + d];
          sc = dot * SCALEF + s_kb[jk];
        }
        s_p[pp] = sc;
      }
      __syncthreads();
      if (tid < 160) {
        int r = tid >> 2, l4 = tid & 3;
        float m = -1e30f;
        for (int kx = l4; kx < 90; kx += 4) m = fmaxf(m, s_p[r * 90 + kx]);
        m = fmaxf(m, __shfl_xor(m, 1, 4));
        m = fmaxf(m, __shfl_xor(m, 2, 4));
        float sum = 0.f;
        for (int kx = l4; kx < 90; kx += 4) {
          float ev = __expf(s_p[r * 90 + kx] - m);
          s_p[r * 90 + kx] = ev;
          sum += ev;
        }
        sum += __shfl_xor(sum, 1, 4);
        sum += __shfl_xor(sum, 2, 4);
        if (l4 == 0) s_den[r] = sum;
      }
      __syncthreads();
      for (int po = tid; po < 400; po += 256) {
        int q = po / 10, d = po % 10;
        float o = 0.f;
        for (int kx = 0; kx < 90; ++kx) o += s_p[q * 90 + kx] * s_v[kx * 10 + d];
        int qr = (q < RCC) ? i * RCC + q : RCL + i * SEGC + (q - RCC);
        p.attn[(b * KK + qr) * DD + h * 10 + d] = o / s_den[q];
      }
    }
    gsync(p.bar, tid);

    // ------- fused OPROJ + LN_ff + full-K FFN + b2/residual/LN_out -------
    // 256 units x 10 rows; ffln and res stay in LDS (no global round-trip).
    {
      unsigned short* s_fa = (unsigned short*)smraw;            // 16*104 bf16
      unsigned short* s_w1 = (unsigned short*)(smraw + 3328);   // 128*104
      unsigned short* s_w2 = (unsigned short*)(smraw + 29952);  // 80*136
      unsigned short* s_h  = (unsigned short*)(smraw + 51712);  // 4*16*40
      float* s_res = (float*)(smraw + 56832);   // 10*80
      float* s_at  = (float*)(smraw + 3328);    // 10*84 (alias s_w1)
      float* s_x2  = (float*)(smraw + 6688);    // 10*84 (alias s_w1)
      float* s_wo  = (float*)(smraw + 10048);   // 80*84 (alias s_w1/s_w2)
      float* s_red = (float*)(smraw + 3328);    // 4*16*80 (alias s_w1)
      float* s_val = (float*)(smraw + 23808);   // 800
      float* s_mu2 = (float*)(smraw + 27008);   // 16
      float* s_ri2 = (float*)(smraw + 27072);   // 16
      int r0 = bid * 10;
      int w = tid >> 6, lane = tid & 63, m = lane & 15, q = lane >> 4;
      unsigned short* s_hw = s_h + w * (16 * 40);  // wave-private h slice
      __syncthreads();  // prior phase LDS reads done
      // zero s_fa (rows 10..15 and cols 80..103 stay zero = K-pad)
      if (tid < 208) {
        int row = tid / 13, ch = tid % 13;
        *reinterpret_cast<uint4*>(&s_fa[row * 104 + ch * 8]) = make_uint4(0, 0, 0, 0);
      }
      // stage attn + x rows (10 x 20 float4)
      if (tid < 200) {
        int row = tid / 20, c4 = tid % 20;
        *reinterpret_cast<float4*>(&s_at[row * 84 + c4 * 4]) =
            *reinterpret_cast<const float4*>(&p.attn[(r0 + row) * DD + c4 * 4]);
        *reinterpret_cast<float4*>(&s_x2[row * 84 + c4 * 4]) =
            *reinterpret_cast<const float4*>(&p.x[(r0 + row) * DD + c4 * 4]);
      }
      for (int k = 0; k < 7; ++k) {
        int idx = tid + k * 256;
        if (idx < 1600) {
          int c = idx / 20, d4 = idx % 20;
          *reinterpret_cast<float4*>(&s_wo[c * 84 + d4 * 4]) =
              *reinterpret_cast<const float4*>(&lWo[c * DD + d4 * 4]);
        }
      }
      __syncthreads();
      // oproj + bias + residual + LN_ff -> s_fa (bf16), s_res
      if (tid < 160) {
        int r = tid >> 4, tx = tid & 15;
        float acc[5] = {};
        for (int d4 = 0; d4 < 20; ++d4) {
          float4 a = *reinterpret_cast<const float4*>(&s_at[r * 84 + d4 * 4]);
#pragma unroll
          for (int j = 0; j < 5; ++j) {
            float4 ww = *reinterpret_cast<const float4*>(&s_wo[(tx + 16 * j) * 84 + d4 * 4]);
            acc[j] += a.x * ww.x + a.y * ww.y + a.z * ww.z + a.w * ww.w;
          }
        }
        float val[5];
        float sm = 0.f, sq = 0.f;
#pragma unroll
        for (int j = 0; j < 5; ++j) {
          int c = tx + 16 * j;
          float v = acc[j] + lbo[c] + s_x2[r * 84 + c];
          val[j] = v;
          s_res[r * 80 + c] = v;
          sm += v; sq += v * v;
        }
        for (int mm = 8; mm >= 1; mm >>= 1) {
          sm += __shfl_xor(sm, mm, 16);
          sq += __shfl_xor(sq, mm, 16);
        }
        float mu = sm * (1.f / DD);
        float ri = rsqrtf(sq * (1.f / DD) - mu * mu + EPSF);
#pragma unroll
        for (int j = 0; j < 5; ++j) {
          int c = tx + 16 * j;
          s_fa[r * 104 + c] = f2bf((val[j] - mu) * ri * ffg_[c] + ffb_[c]);
        }
      }
      __syncthreads();  // s_fa/s_res ready; s_at/s_wo dead
      {  // zero K-pad cols 80..95 of s_w1 (never overwritten by staging)
        int row = tid >> 1, half = tid & 1;
        uint4 z = make_uint4(0, 0, 0, 0);
        *reinterpret_cast<uint4*>(&s_w1[row * 104 + 80 + half * 8]) = z;
      }
      uint4 rw1[5], rw2[5];
#pragma unroll
      for (int k = 0; k < 5; ++k) {  // prefetch chunk 0
        int idx = tid + k * 256;
        int row1 = idx / 10, ch1 = idx % 10;
        rw1[k] = *reinterpret_cast<const uint4*>(&W1l[row1 * DD + ch1 * 8]);
      }
#pragma unroll
      for (int k = 0; k < 5; ++k) {
        int idx = tid + k * 256;
        int row2 = idx >> 4, ch2 = idx & 15;
        rw2[k] = *reinterpret_cast<const uint4*>(&W2l[row2 * FFND + ch2 * 8]);
      }
      f32x4 acc2[5] = {};
      for (int c = 0; c < 16; ++c) {
        int fc0 = c * 128;
        __syncthreads();  // prior chunk MFMA reads done
#pragma unroll
        for (int k = 0; k < 5; ++k) {
          int idx = tid + k * 256;
          int row1 = idx / 10, ch1 = idx % 10;
          *reinterpret_cast<uint4*>(&s_w1[row1 * 104 + ch1 * 8]) = rw1[k];
        }
#pragma unroll
        for (int k = 0; k < 5; ++k) {
          int idx = tid + k * 256;
          int row2 = idx >> 4, ch2 = idx & 15;
          *reinterpret_cast<uint4*>(&s_w2[row2 * 136 + ch2 * 8]) = rw2[k];
        }
        __syncthreads();
        if (c < 15) {  // issue next chunk loads; latency hides under MFMA
          int fn = fc0 + 128;
#pragma unroll
          for (int k = 0; k < 5; ++k) {
            int idx = tid + k * 256;
            int row1 = idx / 10, ch1 = idx % 10;
            rw1[k] = *reinterpret_cast<const uint4*>(&W1l[(fn + row1) * DD + ch1 * 8]);
          }
#pragma unroll
          for (int k = 0; k < 5; ++k) {
            int idx = tid + k * 256;
            int row2 = idx >> 4, ch2 = idx & 15;
            rw2[k] = *reinterpret_cast<const uint4*>(&W2l[row2 * FFND + fn + ch2 * 8]);
          }
        }
        // FFN1: wave w owns ffn cols [w*32, w*32+32) of this chunk
        f32x4 acc1[2] = {};
#pragma unroll
        for (int kk = 0; kk < 3; ++kk) {
          bf16x8 a = *reinterpret_cast<const bf16x8*>(&s_fa[m * 104 + kk * 32 + q * 8]);
#pragma unroll
          for (int ct2 = 0; ct2 < 2; ++ct2) {
            bf16x8 b = *reinterpret_cast<const bf16x8*>(
                &s_w1[(w * 32 + ct2 * 16 + m) * 104 + kk * 32 + q * 8]);
            acc1[ct2] = __builtin_amdgcn_mfma_f32_16x16x32_bf16(a, b, acc1[ct2], 0, 0, 0);
          }
        }
#pragma unroll
        for (int ct2 = 0; ct2 < 2; ++ct2) {
          float bias = b1l[fc0 + w * 32 + ct2 * 16 + m];
#pragma unroll
          for (int r = 0; r < 4; ++r)
            s_hw[(q * 4 + r) * 40 + ct2 * 16 + m] = f2bf(fmaxf(acc1[ct2][r] + bias, 0.f));
        }
        // FFN2 over this wave's 32-wide k-slice (wave-private s_h rows)
        bf16x8 a2 = *reinterpret_cast<const bf16x8*>(&s_hw[m * 40 + q * 8]);
#pragma unroll
        for (int ct = 0; ct < 5; ++ct) {
          bf16x8 b = *reinterpret_cast<const bf16x8*>(
              &s_w2[(ct * 16 + m) * 136 + w * 32 + q * 8]);
          acc2[ct] = __builtin_amdgcn_mfma_f32_16x16x32_bf16(a2, b, acc2[ct], 0, 0, 0);
        }
      }
      __syncthreads();  // MFMA reads of s_w1 done; s_red may overwrite
#pragma unroll
      for (int ct = 0; ct < 5; ++ct)
#pragma unroll
        for (int r = 0; r < 4; ++r)
          s_red[w * 1280 + (q * 4 + r) * 80 + ct * 16 + m] = acc2[ct][r];
      __syncthreads();
      for (int e = tid; e < 800; e += 256) {
        int row = e / 80, cc = e % 80;
        float v = s_red[row * 80 + cc] + s_red[1280 + row * 80 + cc] +
                  s_red[2560 + row * 80 + cc] + s_red[3840 + row * 80 + cc];
        v += b2l[cc] + s_res[row * 80 + cc];
        s_val[e] = v;
      }
      __syncthreads();
      if (tid < 80) {
        int rr = tid >> 3, t8 = tid & 7;
        float sm = 0.f, sq = 0.f;
        for (int d = t8 * 10; d < t8 * 10 + 10; ++d) {
          float v = s_val[rr * 80 + d];
          sm += v; sq += v * v;
        }
        for (int mm = 4; mm >= 1; mm >>= 1) {
          sm += __shfl_xor(sm, mm, 8);
          sq += __shfl_xor(sq, mm, 8);
        }
        if (t8 == 0) {
          float mu = sm * (1.f / DD);
          s_mu2[rr] = mu;
          s_ri2[rr] = rsqrtf(sq * (1.f / DD) - mu * mu + EPSF);
        }
      }
      __syncthreads();
      for (int e = tid; e < 800; e += 256) {
        int row = e / 80, cc = e % 80;
        p.x[(r0 + row) * DD + cc] =
            (s_val[e] - s_mu2[row]) * s_ri2[row] * ogl[cc] + obl[cc];
      }
    }
    gsync(p.bar, tid);
  }

  // ---------------- final projection: 384 units ----------------
  for (int u = bid; u < 384; u += NBLK) {
    float* s_pa = (float*)smraw;               // 64*84
    float* s_pw = (float*)(smraw + 21504);     // 64*84
    int gr0 = (u & 31) * 64;
    int c0 = (u >> 5) * 64;
    int b = gr0 / UU;
    int u0 = gr0 % UU;
    __syncthreads();
    for (int k = 0; k < 5; ++k) {
      int idx = tid + k * 256;
      int row = idx / 20, c4 = idx % 20;
      *reinterpret_cast<float4*>(&s_pa[row * 84 + c4 * 4]) =
          *reinterpret_cast<const float4*>(&p.x[(b * KK + RCL + u0 + row) * DD + c4 * 4]);
      *reinterpret_cast<float4*>(&s_pw[row * 84 + c4 * 4]) =
          *reinterpret_cast<const float4*>(&p.Wp[(c0 + row) * DD + c4 * 4]);
    }
    __syncthreads();
    int ty = tid >> 4, tx = tid & 15;
    float acc[4][4] = {};
    for (int d4 = 0; d4 < 20; ++d4) {
      float4 a[4], w[4];
#pragma unroll
      for (int i2 = 0; i2 < 4; ++i2)
        a[i2] = *reinterpret_cast<const float4*>(&s_pa[(4 * ty + i2) * 84 + d4 * 4]);
#pragma unroll
      for (int j = 0; j < 4; ++j)
        w[j] = *reinterpret_cast<const float4*>(&s_pw[(tx + 16 * j) * 84 + d4 * 4]);
#pragma unroll
      for (int i2 = 0; i2 < 4; ++i2)
#pragma unroll
        for (int j = 0; j < 4; ++j)
          acc[i2][j] += a[i2].x * w[j].x + a[i2].y * w[j].y +
                        a[i2].z * w[j].z + a[i2].w * w[j].w;
    }
    for (int i2 = 0; i2 < 4; ++i2)
      for (int j = 0; j < 4; ++j) {
        int c = c0 + tx + 16 * j;
        p.out[(gr0 + 4 * ty + i2) * OUTD + c] = acc[i2][j] + p.bp[c];
      }
  }
  if (bid == 0 && tid < BB)
    p.out[BB * UU * OUTD + tid] = (float)p.lens[tid];
}

extern "C" void kernel_launch(void* const* d_in, const int* in_sizes, int n_in,
                              void* d_out, int out_size, void* d_ws, size_t ws_size,
                              hipStream_t stream) {
  Prm p;
  p.mel = (const float*)d_in[0];
  p.lng = (const float*)d_in[1];
  p.lnb = (const float*)d_in[2];
  p.Wq  = (const float*)d_in[3];
  p.bq  = (const float*)d_in[4];
  p.Wkv = (const float*)d_in[5];
  p.bkv = (const float*)d_in[6];
  p.Wo  = (const float*)d_in[7];
  p.bo  = (const float*)d_in[8];
  p.ffg = (const float*)d_in[9];
  p.ffb = (const float*)d_in[10];
  p.W1  = (const float*)d_in[11];
  p.b1  = (const float*)d_in[12];
  p.W2  = (const float*)d_in[13];
  p.b2  = (const float*)d_in[14];
  p.og  = (const float*)d_in[15];
  p.ob  = (const float*)d_in[16];
  p.Wp  = (const float*)d_in[17];
  p.bp  = (const float*)d_in[18];
  p.lens = (const int*)d_in[19];
  p.out = (float*)d_out;

  float* ws = (float*)d_ws;
  p.x    = ws;                       // ROWS*DD
  p.qkv  = p.x + ROWS * DD;          // ROWS*240
  p.attn = p.qkv + ROWS * 240;       // ROWS*DD
  p.w1bf = (unsigned short*)(p.attn + ROWS * DD);  // LL*FFND*DD bf16
  p.w2bf = p.w1bf + LL * FFND * DD;                // LL*FFND*DD bf16
  p.bar  = (unsigned int*)((char*)d_ws + (64u << 20));  // far past used region

  k_init<<<1, 64, 0, stream>>>(p.bar);
  k_all<<<NBLK, 256, 0, stream>>>(p);
}

// Round 7
// 1707.960 us; speedup vs baseline: 1.3390x; 1.2709x over previous
//
#include <hip/hip_runtime.h>
#include <math.h>

#define BB 4
#define UU 512
#define DD 80
#define HH 8
#define FFND 2048
#define LL 12
#define SEGC 32
#define LCC 50
#define RCC 8
#define NSEG 16
#define RCL 128
#define KK 640
#define ROWS (BB*KK)        // 2560
#define OUTD 768
#define NBLK 256
#define EPSF 1e-5f
#define SCALEF 0.31622776601683794f  // (D/H)^-0.5

typedef __attribute__((ext_vector_type(8))) short bf16x8;
typedef __attribute__((ext_vector_type(4))) float f32x4;

__device__ inline unsigned short f2bf(float f) {
  unsigned int u = __float_as_uint(f);
  u += 0x7fffu + ((u >> 16) & 1u);
  return (unsigned short)(u >> 16);
}

struct Prm {
  const float *mel, *lng, *lnb, *Wq, *bq, *Wkv, *bkv, *Wo, *bo;
  const float *ffg, *ffb, *W1, *b1, *W2, *b2, *og, *ob, *Wp, *bp;
  const int* lens;
  float *out, *x, *qkv, *attn;
  unsigned short *w1bf, *w2bf;
  unsigned int* bar;
};

// software grid barrier. Exactly ONE wbL2 (release) + ONE invL2 (acquire)
// per block per barrier. Poll uses RELAXED agent loads (sc1, straight to
// the coherence point, NO per-poll cache maintenance — the R6 bug).
__device__ inline void gsync(unsigned int* bar, int tid) {
  __syncthreads();
  if (tid == 0) {
    __builtin_amdgcn_fence(__ATOMIC_RELEASE, "agent");   // wbL2: publish writes
    unsigned my = __hip_atomic_fetch_add(bar, 1u, __ATOMIC_RELAXED,
                                         __HIP_MEMORY_SCOPE_AGENT) + 1u;
    unsigned goal = ((my + NBLK - 1u) / NBLK) * NBLK;
    while (__hip_atomic_load(bar, __ATOMIC_RELAXED,
                             __HIP_MEMORY_SCOPE_AGENT) < goal)
      __builtin_amdgcn_s_sleep(2);
    __builtin_amdgcn_fence(__ATOMIC_ACQUIRE, "agent");   // invL2: see others' writes
  }
  __syncthreads();
}

__global__ void k_init(unsigned int* bar) {
  if (threadIdx.x == 0) *bar = 0u;
}

// One persistent kernel. 256 blocks x 256 threads, 1 block/CU (60032B LDS).
// Barriers: phase0 | qkv(l=0) | 12 x { attn | oproj+FFN+LN_out+qkv(l+1) } = 26.
__global__ __launch_bounds__(256, 1) void k_all(Prm p) {
  __shared__ __align__(16) char smraw[60032];
  const int tid = threadIdx.x;
  const int bid = blockIdx.x;

  // ---------------- phase 0: gather + weight cvt ----------------
  for (int idx = bid * 256 + tid; idx < ROWS * DD; idx += NBLK * 256) {
    int d = idx % DD, row = idx / DD, b = row / KK, j = row % KK;
    int pos;
    if (j < RCL) {
      int i = j >> 3, r = j & 7;
      pos = (i < NSEG - 1) ? (i + 1) * SEGC + r : UU + r;
    } else {
      pos = j - RCL;
    }
    p.x[idx] = p.mel[(b * (UU + RCC) + pos) * DD + d];
  }
  const int NV = (LL * FFND * DD) / 4;
  for (int t = bid * 256 + tid; t < 2 * NV; t += NBLK * 256) {
    const float* src; unsigned short* dst; int i2;
    if (t < NV) { src = p.W1; dst = p.w1bf; i2 = t; }
    else        { src = p.W2; dst = p.w2bf; i2 = t - NV; }
    float4 v = reinterpret_cast<const float4*>(src)[i2];
    ushort4 r;
    r.x = f2bf(v.x); r.y = f2bf(v.y); r.z = f2bf(v.z); r.w = f2bf(v.w);
    reinterpret_cast<ushort4*>(dst)[i2] = r;
  }
  gsync(p.bar, tid);

  // ---------------- QKV layer 0: LN_in + GEMM, 240 units ----------------
  for (int u = bid; u < 240; u += NBLK) {
    float* s_x  = (float*)smraw;               // 32*84
    float* s_w  = (float*)(smraw + 10752);     // 80*84
    float* s_mu = (float*)(smraw + 37632);     // 32
    float* s_ri = (float*)(smraw + 37760);     // 32
    int r0 = (u % 80) * 32;
    int ct = u / 80;
    __syncthreads();
    for (int k = 0; k < 3; ++k) {
      int idx = tid + k * 256;
      if (idx < 640) {
        int row = idx / 20, c4 = idx % 20;
        *reinterpret_cast<float4*>(&s_x[row * 84 + c4 * 4]) =
            *reinterpret_cast<const float4*>(&p.x[(r0 + row) * DD + c4 * 4]);
      }
    }
    const float* Wbase = (ct == 0) ? p.Wq : (ct == 1 ? p.Wkv : (p.Wkv + 80 * DD));
    for (int k = 0; k < 7; ++k) {
      int idx = tid + k * 256;
      if (idx < 1600) {
        int c = idx / 20, d4 = idx % 20;
        *reinterpret_cast<float4*>(&s_w[c * 84 + d4 * 4]) =
            *reinterpret_cast<const float4*>(&Wbase[c * DD + d4 * 4]);
      }
    }
    __syncthreads();
    {
      int rr = tid >> 3, t8 = tid & 7;
      float sm = 0.f, sq = 0.f;
      for (int d = t8 * 10; d < t8 * 10 + 10; ++d) {
        float v = s_x[rr * 84 + d];
        sm += v; sq += v * v;
      }
      for (int mm = 4; mm >= 1; mm >>= 1) {
        sm += __shfl_xor(sm, mm, 8);
        sq += __shfl_xor(sq, mm, 8);
      }
      if (t8 == 0) {
        float mu = sm * (1.f / DD);
        s_mu[rr] = mu;
        s_ri[rr] = rsqrtf(sq * (1.f / DD) - mu * mu + EPSF);
      }
    }
    __syncthreads();
    for (int k = 0; k < 10; ++k) {
      int e = tid + k * 256;
      int row = e / 80, d = e % 80;
      s_x[row * 84 + d] = (s_x[row * 84 + d] - s_mu[row]) * s_ri[row] * p.lng[d] + p.lnb[d];
    }
    __syncthreads();
    int ty = tid >> 4, tx = tid & 15;
    float acc[2][5] = {};
    for (int d4 = 0; d4 < 20; ++d4) {
      float4 a0 = *reinterpret_cast<const float4*>(&s_x[(2 * ty) * 84 + d4 * 4]);
      float4 a1 = *reinterpret_cast<const float4*>(&s_x[(2 * ty + 1) * 84 + d4 * 4]);
#pragma unroll
      for (int j = 0; j < 5; ++j) {
        float4 w = *reinterpret_cast<const float4*>(&s_w[(tx + 16 * j) * 84 + d4 * 4]);
        acc[0][j] += a0.x * w.x + a0.y * w.y + a0.z * w.z + a0.w * w.w;
        acc[1][j] += a1.x * w.x + a1.y * w.y + a1.z * w.z + a1.w * w.w;
      }
    }
    const float* bias = (ct == 0) ? p.bq : (p.bkv + (ct == 2 ? 80 : 0));
    for (int i2 = 0; i2 < 2; ++i2)
      for (int j = 0; j < 5; ++j) {
        int c = tx + 16 * j;
        int grow = r0 + 2 * ty + i2;
        p.qkv[grow * 240 + ct * 80 + c] = acc[i2][j] + bias[c];
      }
  }
  gsync(p.bar, tid);

  for (int l = 0; l < LL; ++l) {
    const float* lWo  = p.Wo  + l * DD * DD;
    const float* lbo  = p.bo  + l * DD;
    const float* ffg_ = p.ffg + l * DD;
    const float* ffb_ = p.ffb + l * DD;
    const unsigned short* W1l = p.w1bf + l * FFND * DD;
    const float* b1l = p.b1 + l * FFND;
    const unsigned short* W2l = p.w2bf + l * FFND * DD;
    const float* b2l = p.b2 + l * DD;
    const float* ogl = p.og + l * DD;
    const float* obl = p.ob + l * DD;

    // ---------------- ATTN: 512 units (i,h,b) ----------------
    for (int u = bid; u < 512; u += NBLK) {
      float* s_k   = (float*)smraw;              // 900
      float* s_v   = (float*)(smraw + 3600);     // 900
      float* s_q   = (float*)(smraw + 7200);     // 400
      float* s_p   = (float*)(smraw + 8800);     // 3600
      float* s_kb  = (float*)(smraw + 23200);    // 90
      float* s_den = (float*)(smraw + 23560);    // 40
      int i = u & 15, h = (u >> 4) & 7, b = u >> 7;
      int s = i * SEGC - LCC; if (s < 0) s = 0;
      int e = (i + 1) * SEGC;
      int nk = RCC + (e - s);  // <= 90
      int len = p.lens[b];
      __syncthreads();
      if (tid < 90 && tid < nk) {
        int j = tid;
        int kr = (j < RCC) ? i * RCC + j : RCL + s + (j - RCC);
        const float* kp = &p.qkv[(b * KK + kr) * 240 + 80 + h * 10];
        const float* vp = &p.qkv[(b * KK + kr) * 240 + 160 + h * 10];
#pragma unroll
        for (int d = 0; d < 10; ++d) { s_k[j * 10 + d] = kp[d]; s_v[j * 10 + d] = vp[d]; }
        s_kb[j] = (kr >= len + RCL) ? -1e8f : 0.f;
      }
      if (tid >= 128 && tid < 168) {
        int j = tid - 128;
        int qr = (j < RCC) ? i * RCC + j : RCL + i * SEGC + (j - RCC);
        const float* qp = &p.qkv[(b * KK + qr) * 240 + h * 10];
#pragma unroll
        for (int d = 0; d < 10; ++d) s_q[j * 10 + d] = qp[d];
      }
      __syncthreads();
      for (int pp = tid; pp < 3600; pp += 256) {
        int q = pp / 90, jk = pp % 90;
        float sc = -1e30f;
        if (jk < nk) {
          float dot = 0.f;
#pragma unroll
          for (int d = 0; d < 10; ++d) dot += s_q[q * 10 + d] * s_k[jk * 10 + d];
          sc = dot * SCALEF + s_kb[jk];
        }
        s_p[pp] = sc;
      }
      __syncthreads();
      if (tid < 160) {
        int r = tid >> 2, l4 = tid & 3;
        float m = -1e30f;
        for (int kx = l4; kx < 90; kx += 4) m = fmaxf(m, s_p[r * 90 + kx]);
        m = fmaxf(m, __shfl_xor(m, 1, 4));
        m = fmaxf(m, __shfl_xor(m, 2, 4));
        float sum = 0.f;
        for (int kx = l4; kx < 90; kx += 4) {
          float ev = __expf(s_p[r * 90 + kx] - m);
          s_p[r * 90 + kx] = ev;
          sum += ev;
        }
        sum += __shfl_xor(sum, 1, 4);
        sum += __shfl_xor(sum, 2, 4);
        if (l4 == 0) s_den[r] = sum;
      }
      __syncthreads();
      for (int po = tid; po < 400; po += 256) {
        int q = po / 10, d = po % 10;
        float o = 0.f;
        for (int kx = 0; kx < 90; ++kx) o += s_p[q * 90 + kx] * s_v[kx * 10 + d];
        int qr = (q < RCC) ? i * RCC + q : RCL + i * SEGC + (q - RCC);
        p.attn[(b * KK + qr) * DD + h * 10 + d] = o / s_den[q];
      }
    }
    gsync(p.bar, tid);

    // --- fused OPROJ + LN_ff + full-K FFN + b2/residual/LN_out + QKV(l+1) ---
    // 256 units x 10 rows.
    {
      unsigned short* s_fa = (unsigned short*)smraw;            // 16*104 bf16
      unsigned short* s_w1 = (unsigned short*)(smraw + 3328);   // 128*104
      unsigned short* s_w2 = (unsigned short*)(smraw + 29952);  // 80*136
      unsigned short* s_h  = (unsigned short*)(smraw + 51712);  // 4*16*40
      float* s_res = (float*)(smraw + 56832);   // 10*80
      float* s_at  = (float*)(smraw + 3328);    // 10*84 (alias s_w1)
      float* s_x2  = (float*)(smraw + 6688);    // 10*84 (alias s_w1)
      float* s_wo  = (float*)(smraw + 10048);   // 80*84 (alias s_w1/s_w2)
      float* s_red = (float*)(smraw + 3328);    // 4*16*80 (alias s_w1)
      float* s_val = (float*)(smraw + 23808);   // 800
      float* s_mu2 = (float*)(smraw + 27008);   // 16
      float* s_ri2 = (float*)(smraw + 27072);   // 16
      int r0 = bid * 10;
      int w = tid >> 6, lane = tid & 63, m = lane & 15, q = lane >> 4;
      unsigned short* s_hw = s_h + w * (16 * 40);  // wave-private h slice
      __syncthreads();  // prior phase LDS reads done
      // zero s_fa (rows 10..15 and cols 80..103 stay zero = K-pad)
      if (tid < 208) {
        int row = tid / 13, ch = tid % 13;
        *reinterpret_cast<uint4*>(&s_fa[row * 104 + ch * 8]) = make_uint4(0, 0, 0, 0);
      }
      // stage attn + x rows (10 x 20 float4)
      if (tid < 200) {
        int row = tid / 20, c4 = tid % 20;
        *reinterpret_cast<float4*>(&s_at[row * 84 + c4 * 4]) =
            *reinterpret_cast<const float4*>(&p.attn[(r0 + row) * DD + c4 * 4]);
        *reinterpret_cast<float4*>(&s_x2[row * 84 + c4 * 4]) =
            *reinterpret_cast<const float4*>(&p.x[(r0 + row) * DD + c4 * 4]);
      }
      for (int k = 0; k < 7; ++k) {
        int idx = tid + k * 256;
        if (idx < 1600) {
          int c = idx / 20, d4 = idx % 20;
          *reinterpret_cast<float4*>(&s_wo[c * 84 + d4 * 4]) =
              *reinterpret_cast<const float4*>(&lWo[c * DD + d4 * 4]);
        }
      }
      __syncthreads();
      // oproj + bias + residual + LN_ff -> s_fa (bf16), s_res
      if (tid < 160) {
        int r = tid >> 4, tx = tid & 15;
        float acc[5] = {};
        for (int d4 = 0; d4 < 20; ++d4) {
          float4 a = *reinterpret_cast<const float4*>(&s_at[r * 84 + d4 * 4]);
#pragma unroll
          for (int j = 0; j < 5; ++j) {
            float4 ww = *reinterpret_cast<const float4*>(&s_wo[(tx + 16 * j) * 84 + d4 * 4]);
            acc[j] += a.x * ww.x + a.y * ww.y + a.z * ww.z + a.w * ww.w;
          }
        }
        float val[5];
        float sm = 0.f, sq = 0.f;
#pragma unroll
        for (int j = 0; j < 5; ++j) {
          int c = tx + 16 * j;
          float v = acc[j] + lbo[c] + s_x2[r * 84 + c];
          val[j] = v;
          s_res[r * 80 + c] = v;
          sm += v; sq += v * v;
        }
        for (int mm = 8; mm >= 1; mm >>= 1) {
          sm += __shfl_xor(sm, mm, 16);
          sq += __shfl_xor(sq, mm, 16);
        }
        float mu = sm * (1.f / DD);
        float ri = rsqrtf(sq * (1.f / DD) - mu * mu + EPSF);
#pragma unroll
        for (int j = 0; j < 5; ++j) {
          int c = tx + 16 * j;
          s_fa[r * 104 + c] = f2bf((val[j] - mu) * ri * ffg_[c] + ffb_[c]);
        }
      }
      __syncthreads();  // s_fa/s_res ready; s_at/s_wo dead
      {  // zero K-pad cols 80..95 of s_w1 (never overwritten by staging)
        int row = tid >> 1, half = tid & 1;
        uint4 z = make_uint4(0, 0, 0, 0);
        *reinterpret_cast<uint4*>(&s_w1[row * 104 + 80 + half * 8]) = z;
      }
      uint4 rw1[5], rw2[5];
#pragma unroll
      for (int k = 0; k < 5; ++k) {  // prefetch chunk 0
        int idx = tid + k * 256;
        int row1 = idx / 10, ch1 = idx % 10;
        rw1[k] = *reinterpret_cast<const uint4*>(&W1l[row1 * DD + ch1 * 8]);
      }
#pragma unroll
      for (int k = 0; k < 5; ++k) {
        int idx = tid + k * 256;
        int row2 = idx >> 4, ch2 = idx & 15;
        rw2[k] = *reinterpret_cast<const uint4*>(&W2l[row2 * FFND + ch2 * 8]);
      }
      f32x4 acc2[5] = {};
      for (int c = 0; c < 16; ++c) {
        int fc0 = c * 128;
        __syncthreads();  // prior chunk MFMA reads done
#pragma unroll
        for (int k = 0; k < 5; ++k) {
          int idx = tid + k * 256;
          int row1 = idx / 10, ch1 = idx % 10;
          *reinterpret_cast<uint4*>(&s_w1[row1 * 104 + ch1 * 8]) = rw1[k];
        }
#pragma unroll
        for (int k = 0; k < 5; ++k) {
          int idx = tid + k * 256;
          int row2 = idx >> 4, ch2 = idx & 15;
          *reinterpret_cast<uint4*>(&s_w2[row2 * 136 + ch2 * 8]) = rw2[k];
        }
        __syncthreads();
        if (c < 15) {  // issue next chunk loads; latency hides under MFMA
          int fn = fc0 + 128;
#pragma unroll
          for (int k = 0; k < 5; ++k) {
            int idx = tid + k * 256;
            int row1 = idx / 10, ch1 = idx % 10;
            rw1[k] = *reinterpret_cast<const uint4*>(&W1l[(fn + row1) * DD + ch1 * 8]);
          }
#pragma unroll
          for (int k = 0; k < 5; ++k) {
            int idx = tid + k * 256;
            int row2 = idx >> 4, ch2 = idx & 15;
            rw2[k] = *reinterpret_cast<const uint4*>(&W2l[row2 * FFND + fn + ch2 * 8]);
          }
        }
        // FFN1: wave w owns ffn cols [w*32, w*32+32) of this chunk
        f32x4 acc1[2] = {};
#pragma unroll
        for (int kk = 0; kk < 3; ++kk) {
          bf16x8 a = *reinterpret_cast<const bf16x8*>(&s_fa[m * 104 + kk * 32 + q * 8]);
#pragma unroll
          for (int ct2 = 0; ct2 < 2; ++ct2) {
            bf16x8 b = *reinterpret_cast<const bf16x8*>(
                &s_w1[(w * 32 + ct2 * 16 + m) * 104 + kk * 32 + q * 8]);
            acc1[ct2] = __builtin_amdgcn_mfma_f32_16x16x32_bf16(a, b, acc1[ct2], 0, 0, 0);
          }
        }
#pragma unroll
        for (int ct2 = 0; ct2 < 2; ++ct2) {
          float bias = b1l[fc0 + w * 32 + ct2 * 16 + m];
#pragma unroll
          for (int r = 0; r < 4; ++r)
            s_hw[(q * 4 + r) * 40 + ct2 * 16 + m] = f2bf(fmaxf(acc1[ct2][r] + bias, 0.f));
        }
        // FFN2 over this wave's 32-wide k-slice (wave-private s_h rows)
        bf16x8 a2 = *reinterpret_cast<const bf16x8*>(&s_hw[m * 40 + q * 8]);
#pragma unroll
        for (int ct = 0; ct < 5; ++ct) {
          bf16x8 b = *reinterpret_cast<const bf16x8*>(
              &s_w2[(ct * 16 + m) * 136 + w * 32 + q * 8]);
          acc2[ct] = __builtin_amdgcn_mfma_f32_16x16x32_bf16(a2, b, acc2[ct], 0, 0, 0);
        }
      }
      __syncthreads();  // MFMA reads of s_w1 done; s_red may overwrite
#pragma unroll
      for (int ct = 0; ct < 5; ++ct)
#pragma unroll
        for (int r = 0; r < 4; ++r)
          s_red[w * 1280 + (q * 4 + r) * 80 + ct * 16 + m] = acc2[ct][r];
      __syncthreads();
      for (int e = tid; e < 800; e += 256) {
        int row = e / 80, cc = e % 80;
        float v = s_red[row * 80 + cc] + s_red[1280 + row * 80 + cc] +
                  s_red[2560 + row * 80 + cc] + s_red[3840 + row * 80 + cc];
        v += b2l[cc] + s_res[row * 80 + cc];
        s_val[e] = v;
      }
      __syncthreads();
      if (tid < 80) {
        int rr = tid >> 3, t8 = tid & 7;
        float sm = 0.f, sq = 0.f;
        for (int d = t8 * 10; d < t8 * 10 + 10; ++d) {
          float v = s_val[rr * 80 + d];
          sm += v; sq += v * v;
        }
        for (int mm = 4; mm >= 1; mm >>= 1) {
          sm += __shfl_xor(sm, mm, 8);
          sq += __shfl_xor(sq, mm, 8);
        }
        if (t8 == 0) {
          float mu = sm * (1.f / DD);
          s_mu2[rr] = mu;
          s_ri2[rr] = rsqrtf(sq * (1.f / DD) - mu * mu + EPSF);
        }
      }
      __syncthreads();
      for (int e = tid; e < 800; e += 256) {
        int row = e / 80, cc = e % 80;
        float xv = (s_val[e] - s_mu2[row]) * s_ri2[row] * ogl[cc] + obl[cc];
        p.x[(r0 + row) * DD + cc] = xv;
        s_val[e] = xv;                     // keep x rows in LDS for qkv(l+1)
      }
      // ---- fused QKV(l+1): row-local LN_in + GEMM over own 10 rows ----
      if (l < LL - 1) {
        const float* lng_n = p.lng + (l + 1) * DD;
        const float* lnb_n = p.lnb + (l + 1) * DD;
        __syncthreads();
        if (tid < 80) {
          int rr = tid >> 3, t8 = tid & 7;
          float sm = 0.f, sq = 0.f;
          for (int d = t8 * 10; d < t8 * 10 + 10; ++d) {
            float v = s_val[rr * 80 + d];
            sm += v; sq += v * v;
          }
          for (int mm = 4; mm >= 1; mm >>= 1) {
            sm += __shfl_xor(sm, mm, 8);
            sq += __shfl_xor(sq, mm, 8);
          }
          if (t8 == 0) {
            float mu = sm * (1.f / DD);
            s_mu2[rr] = mu;
            s_ri2[rr] = rsqrtf(sq * (1.f / DD) - mu * mu + EPSF);
          }
        }
        __syncthreads();
        for (int e = tid; e < 800; e += 256) {
          int row = e / 80, cc = e % 80;
          s_val[e] = (s_val[e] - s_mu2[row]) * s_ri2[row] * lng_n[cc] + lnb_n[cc];
        }
        __syncthreads();
        if (tid < 240) {
          const float* Wn;
          float bn;
          if (tid < 80) {
            Wn = p.Wq + (l + 1) * DD * DD + tid * DD;
            bn = p.bq[(l + 1) * DD + tid];
          } else {
            Wn = p.Wkv + (l + 1) * 2 * DD * DD + (tid - 80) * DD;
            bn = p.bkv[(l + 1) * 2 * DD + (tid - 80)];
          }
          float acc[10] = {};
          for (int d4 = 0; d4 < 20; ++d4) {
            float4 wv = *reinterpret_cast<const float4*>(&Wn[d4 * 4]);
#pragma unroll
            for (int r = 0; r < 10; ++r) {
              float4 sv = *reinterpret_cast<const float4*>(&s_val[r * 80 + d4 * 4]);
              acc[r] += sv.x * wv.x + sv.y * wv.y + sv.z * wv.z + sv.w * wv.w;
            }
          }
#pragma unroll
          for (int r = 0; r < 10; ++r)
            p.qkv[(r0 + r) * 240 + tid] = acc[r] + bn;
        }
      }
    }
    gsync(p.bar, tid);
  }

  // ---------------- final projection: 384 units ----------------
  for (int u = bid; u < 384; u += NBLK) {
    float* s_pa = (float*)smraw;               // 64*84
    float* s_pw = (float*)(smraw + 21504);     // 64*84
    int gr0 = (u & 31) * 64;
    int c0 = (u >> 5) * 64;
    int b = gr0 / UU;
    int u0 = gr0 % UU;
    __syncthreads();
    for (int k = 0; k < 5; ++k) {
      int idx = tid + k * 256;
      int row = idx / 20, c4 = idx % 20;
      *reinterpret_cast<float4*>(&s_pa[row * 84 + c4 * 4]) =
          *reinterpret_cast<const float4*>(&p.x[(b * KK + RCL + u0 + row) * DD + c4 * 4]);
      *reinterpret_cast<float4*>(&s_pw[row * 84 + c4 * 4]) =
          *reinterpret_cast<const float4*>(&p.Wp[(c0 + row) * DD + c4 * 4]);
    }
    __syncthreads();
    int ty = tid >> 4, tx = tid & 15;
    float acc[4][4] = {};
    for (int d4 = 0; d4 < 20; ++d4) {
      float4 a[4], w[4];
#pragma unroll
      for (int i2 = 0; i2 < 4; ++i2)
        a[i2] = *reinterpret_cast<const float4*>(&s_pa[(4 * ty + i2) * 84 + d4 * 4]);
#pragma unroll
      for (int j = 0; j < 4; ++j)
        w[j] = *reinterpret_cast<const float4*>(&s_pw[(tx + 16 * j) * 84 + d4 * 4]);
#pragma unroll
      for (int i2 = 0; i2 < 4; ++i2)
#pragma unroll
        for (int j = 0; j < 4; ++j)
          acc[i2][j] += a[i2].x * w[j].x + a[i2].y * w[j].y +
                        a[i2].z * w[j].z + a[i2].w * w[j].w;
    }
    for (int i2 = 0; i2 < 4; ++i2)
      for (int j = 0; j < 4; ++j) {
        int c = c0 + tx + 16 * j;
        p.out[(gr0 + 4 * ty + i2) * OUTD + c] = acc[i2][j] + p.bp[c];
      }
  }
  if (bid == 0 && tid < BB)
    p.out[BB * UU * OUTD + tid] = (float)p.lens[tid];
}

extern "C" void kernel_launch(void* const* d_in, const int* in_sizes, int n_in,
                              void* d_out, int out_size, void* d_ws, size_t ws_size,
                              hipStream_t stream) {
  Prm p;
  p.mel = (const float*)d_in[0];
  p.lng = (const float*)d_in[1];
  p.lnb = (const float*)d_in[2];
  p.Wq  = (const float*)d_in[3];
  p.bq  = (const float*)d_in[4];
  p.Wkv = (const float*)d_in[5];
  p.bkv = (const float*)d_in[6];
  p.Wo  = (const float*)d_in[7];
  p.bo  = (const float*)d_in[8];
  p.ffg = (const float*)d_in[9];
  p.ffb = (const float*)d_in[10];
  p.W1  = (const float*)d_in[11];
  p.b1  = (const float*)d_in[12];
  p.W2  = (const float*)d_in[13];
  p.b2  = (const float*)d_in[14];
  p.og  = (const float*)d_in[15];
  p.ob  = (const float*)d_in[16];
  p.Wp  = (const float*)d_in[17];
  p.bp  = (const float*)d_in[18];
  p.lens = (const int*)d_in[19];
  p.out = (float*)d_out;

  float* ws = (float*)d_ws;
  p.x    = ws;                       // ROWS*DD
  p.qkv  = p.x + ROWS * DD;          // ROWS*240
  p.attn = p.qkv + ROWS * 240;       // ROWS*DD
  p.w1bf = (unsigned short*)(p.attn + ROWS * DD);  // LL*FFND*DD bf16
  p.w2bf = p.w1bf + LL * FFND * DD;                // LL*FFND*DD bf16
  p.bar  = (unsigned int*)((char*)d_ws + (64u << 20));  // far past used region

  k_init<<<1, 64, 0, stream>>>(p.bar);
  k_all<<<NBLK, 256, 0, stream>>>(p);
}

// Round 8
// 906.028 us; speedup vs baseline: 2.5242x; 1.8851x over previous
//
#include <hip/hip_runtime.h>
#include <math.h>

#define BB 4
#define UU 512
#define DD 80
#define HH 8
#define FFND 2048
#define LL 12
#define SEGC 32
#define LCC 50
#define RCC 8
#define NSEG 16
#define RCL 128
#define KK 640
#define ROWS (BB*KK)        // 2560
#define OUTD 768
#define EPSF 1e-5f
#define SCALEF 0.31622776601683794f  // (D/H)^-0.5

typedef __attribute__((ext_vector_type(8))) short bf16x8;
typedef __attribute__((ext_vector_type(4))) float f32x4;

__device__ inline unsigned short f2bf(float f) {
  unsigned int u = __float_as_uint(f);
  u += 0x7fffu + ((u >> 16) & 1u);
  return (unsigned short)(u >> 16);
}

// ---------------- gather: x0 = concat(rc, utt) ----------------
__global__ __launch_bounds__(256) void k_gather(const float* __restrict__ mel,
                                                float* __restrict__ x) {
  int idx = blockIdx.x * 256 + threadIdx.x;
  if (idx >= ROWS * DD) return;
  int d = idx % DD;
  int row = idx / DD;
  int b = row / KK;
  int j = row % KK;
  int pos;
  if (j < RCL) {
    int i = j >> 3, r = j & 7;
    pos = (i < NSEG - 1) ? (i + 1) * SEGC + r : UU + r;
  } else {
    pos = j - RCL;
  }
  x[idx] = mel[(b * (UU + RCC) + pos) * DD + d];
}

// ---------------- convert W1/W2 (all layers) fp32 -> bf16 ----------------
__global__ __launch_bounds__(256) void k_cvt(const float* __restrict__ W1,
                                             const float* __restrict__ W2,
                                             unsigned short* __restrict__ o1,
                                             unsigned short* __restrict__ o2) {
  const int NV = (LL * FFND * DD) / 4;
  int t = blockIdx.x * 256 + threadIdx.x;
  const float* src;
  unsigned short* dst;
  int i;
  if (t < NV) { src = W1; dst = o1; i = t; }
  else        { src = W2; dst = o2; i = t - NV; }
  float4 v = reinterpret_cast<const float4*>(src)[i];
  ushort4 r;
  r.x = f2bf(v.x); r.y = f2bf(v.y); r.z = f2bf(v.z); r.w = f2bf(v.w);
  reinterpret_cast<ushort4*>(dst)[i] = r;
}

// ---------------- A: LN_in fused + QKV GEMM (layer 0 only) ----------------
__global__ __launch_bounds__(256) void k_qkv(
    const float* __restrict__ x, float* __restrict__ qkv,
    const float* __restrict__ Wq, const float* __restrict__ bq,
    const float* __restrict__ Wkv, const float* __restrict__ bkv,
    const float* __restrict__ lg, const float* __restrict__ lb) {
  __shared__ float s_x[32 * 84];
  __shared__ float s_w[80 * 84];
  __shared__ float s_mu[32], s_ri[32];
  int tid = threadIdx.x;
  int r0 = blockIdx.x * 32;
  int ct = blockIdx.y;
  for (int k = 0; k < 3; ++k) {
    int idx = tid + k * 256;
    if (idx < 640) {
      int row = idx / 20, c4 = idx % 20;
      *reinterpret_cast<float4*>(&s_x[row * 84 + c4 * 4]) =
          *reinterpret_cast<const float4*>(&x[(r0 + row) * DD + c4 * 4]);
    }
  }
  const float* Wbase = (ct == 0) ? Wq : (ct == 1 ? Wkv : (Wkv + 80 * DD));
  for (int k = 0; k < 7; ++k) {
    int idx = tid + k * 256;
    if (idx < 1600) {
      int c = idx / 20, d4 = idx % 20;
      *reinterpret_cast<float4*>(&s_w[c * 84 + d4 * 4]) =
          *reinterpret_cast<const float4*>(&Wbase[c * DD + d4 * 4]);
    }
  }
  __syncthreads();
  {
    int rr = tid >> 3, t8 = tid & 7;
    float sm = 0.f, sq = 0.f;
    for (int d = t8 * 10; d < t8 * 10 + 10; ++d) {
      float v = s_x[rr * 84 + d];
      sm += v; sq += v * v;
    }
    for (int m = 4; m >= 1; m >>= 1) {
      sm += __shfl_xor(sm, m, 8);
      sq += __shfl_xor(sq, m, 8);
    }
    if (t8 == 0) {
      float mu = sm * (1.f / DD);
      s_mu[rr] = mu;
      s_ri[rr] = rsqrtf(sq * (1.f / DD) - mu * mu + EPSF);
    }
  }
  __syncthreads();
  for (int k = 0; k < 10; ++k) {
    int e = tid + k * 256;
    int row = e / 80, d = e % 80;
    s_x[row * 84 + d] = (s_x[row * 84 + d] - s_mu[row]) * s_ri[row] * lg[d] + lb[d];
  }
  __syncthreads();
  int ty = tid >> 4, tx = tid & 15;
  float acc[2][5] = {};
  for (int d4 = 0; d4 < 20; ++d4) {
    float4 a0 = *reinterpret_cast<const float4*>(&s_x[(2 * ty) * 84 + d4 * 4]);
    float4 a1 = *reinterpret_cast<const float4*>(&s_x[(2 * ty + 1) * 84 + d4 * 4]);
#pragma unroll
    for (int j = 0; j < 5; ++j) {
      float4 w = *reinterpret_cast<const float4*>(&s_w[(tx + 16 * j) * 84 + d4 * 4]);
      acc[0][j] += a0.x * w.x + a0.y * w.y + a0.z * w.z + a0.w * w.w;
      acc[1][j] += a1.x * w.x + a1.y * w.y + a1.z * w.z + a1.w * w.w;
    }
  }
  const float* bias = (ct == 0) ? bq : (bkv + (ct == 2 ? 80 : 0));
  for (int i2 = 0; i2 < 2; ++i2)
    for (int j = 0; j < 5; ++j) {
      int c = tx + 16 * j;
      int grow = r0 + 2 * ty + i2;
      qkv[grow * 240 + ct * 80 + c] = acc[i2][j] + bias[c];
    }
}

// ---------------- B: masked segmented attention ----------------
__global__ __launch_bounds__(256) void k_attn(const float* __restrict__ qkv,
                                              float* __restrict__ attn,
                                              const int* __restrict__ lengths) {
  int i = blockIdx.x, h = blockIdx.y, b = blockIdx.z;
  int tid = threadIdx.x;
  int s = i * SEGC - LCC; if (s < 0) s = 0;
  int e = (i + 1) * SEGC;
  int nk = RCC + (e - s);  // <= 90
  __shared__ float s_k[90 * 10], s_v[90 * 10], s_q[40 * 10];
  __shared__ float s_p[40 * 90], s_kb[90], s_den[40];
  int len = lengths[b];
  if (tid < 90 && tid < nk) {
    int j = tid;
    int kr = (j < RCC) ? i * RCC + j : RCL + s + (j - RCC);
    const float* kp = &qkv[(b * KK + kr) * 240 + 80 + h * 10];
    const float* vp = &qkv[(b * KK + kr) * 240 + 160 + h * 10];
#pragma unroll
    for (int d = 0; d < 10; ++d) { s_k[j * 10 + d] = kp[d]; s_v[j * 10 + d] = vp[d]; }
    s_kb[j] = (kr >= len + RCL) ? -1e8f : 0.f;
  }
  if (tid >= 128 && tid < 168) {
    int j = tid - 128;
    int qr = (j < RCC) ? i * RCC + j : RCL + i * SEGC + (j - RCC);
    const float* qp = &qkv[(b * KK + qr) * 240 + h * 10];
#pragma unroll
    for (int d = 0; d < 10; ++d) s_q[j * 10 + d] = qp[d];
  }
  __syncthreads();
  for (int p = tid; p < 3600; p += 256) {
    int q = p / 90, jk = p % 90;
    float sc = -1e30f;
    if (jk < nk) {
      float dot = 0.f;
#pragma unroll
      for (int d = 0; d < 10; ++d) dot += s_q[q * 10 + d] * s_k[jk * 10 + d];
      sc = dot * SCALEF + s_kb[jk];
    }
    s_p[p] = sc;
  }
  __syncthreads();
  if (tid < 160) {
    int r = tid >> 2, l4 = tid & 3;
    float m = -1e30f;
    for (int kx = l4; kx < 90; kx += 4) m = fmaxf(m, s_p[r * 90 + kx]);
    m = fmaxf(m, __shfl_xor(m, 1, 4));
    m = fmaxf(m, __shfl_xor(m, 2, 4));
    float sum = 0.f;
    for (int kx = l4; kx < 90; kx += 4) {
      float ev = __expf(s_p[r * 90 + kx] - m);
      s_p[r * 90 + kx] = ev;
      sum += ev;
    }
    sum += __shfl_xor(sum, 1, 4);
    sum += __shfl_xor(sum, 2, 4);
    if (l4 == 0) s_den[r] = sum;
  }
  __syncthreads();
  for (int po = tid; po < 400; po += 256) {
    int q = po / 10, d = po % 10;
    float o = 0.f;
    for (int kx = 0; kx < 90; ++kx) o += s_p[q * 90 + kx] * s_v[kx * 10 + d];
    int qr = (q < RCC) ? i * RCC + q : RCL + i * SEGC + (q - RCC);
    attn[(b * KK + qr) * DD + h * 10 + d] = o / s_den[q];
  }
}

// --- fused: OPROJ + LN_ff + full-K FFN + b2/residual/LN_out + QKV(l+1) ---
// grid 256 x 10 rows, block 256. Bodies verbatim from the verified R7 phase.
__global__ __launch_bounds__(256) void k_fused(
    const float* __restrict__ attn, float* __restrict__ x,
    float* __restrict__ qkv,
    const float* __restrict__ Wo, const float* __restrict__ bo,
    const float* __restrict__ ffg, const float* __restrict__ ffb,
    const unsigned short* __restrict__ W1l, const float* __restrict__ b1l,
    const unsigned short* __restrict__ W2l, const float* __restrict__ b2l,
    const float* __restrict__ ogl, const float* __restrict__ obl,
    const float* __restrict__ lng_n, const float* __restrict__ lnb_n,
    const float* __restrict__ Wq_n, const float* __restrict__ bq_n,
    const float* __restrict__ Wkv_n, const float* __restrict__ bkv_n,
    int do_qkv) {
  __shared__ __align__(16) char smraw[60032];
  unsigned short* s_fa = (unsigned short*)smraw;            // 16*104 bf16
  unsigned short* s_w1 = (unsigned short*)(smraw + 3328);   // 128*104
  unsigned short* s_w2 = (unsigned short*)(smraw + 29952);  // 80*136
  unsigned short* s_h  = (unsigned short*)(smraw + 51712);  // 4*16*40
  float* s_res = (float*)(smraw + 56832);   // 10*80
  float* s_at  = (float*)(smraw + 3328);    // 10*84 (alias s_w1)
  float* s_x2  = (float*)(smraw + 6688);    // 10*84 (alias s_w1)
  float* s_wo  = (float*)(smraw + 10048);   // 80*84 (alias s_w1/s_w2)
  float* s_red = (float*)(smraw + 3328);    // 4*16*80 (alias s_w1)
  float* s_val = (float*)(smraw + 23808);   // 800
  float* s_mu2 = (float*)(smraw + 27008);   // 16
  float* s_ri2 = (float*)(smraw + 27072);   // 16
  int tid = threadIdx.x;
  int r0 = blockIdx.x * 10;
  int w = tid >> 6, lane = tid & 63, m = lane & 15, q = lane >> 4;
  unsigned short* s_hw = s_h + w * (16 * 40);  // wave-private h slice
  // zero s_fa (rows 10..15 and cols 80..103 stay zero = K-pad)
  if (tid < 208) {
    int row = tid / 13, ch = tid % 13;
    *reinterpret_cast<uint4*>(&s_fa[row * 104 + ch * 8]) = make_uint4(0, 0, 0, 0);
  }
  // stage attn + x rows (10 x 20 float4)
  if (tid < 200) {
    int row = tid / 20, c4 = tid % 20;
    *reinterpret_cast<float4*>(&s_at[row * 84 + c4 * 4]) =
        *reinterpret_cast<const float4*>(&attn[(r0 + row) * DD + c4 * 4]);
    *reinterpret_cast<float4*>(&s_x2[row * 84 + c4 * 4]) =
        *reinterpret_cast<const float4*>(&x[(r0 + row) * DD + c4 * 4]);
  }
  for (int k = 0; k < 7; ++k) {
    int idx = tid + k * 256;
    if (idx < 1600) {
      int c = idx / 20, d4 = idx % 20;
      *reinterpret_cast<float4*>(&s_wo[c * 84 + d4 * 4]) =
          *reinterpret_cast<const float4*>(&Wo[c * DD + d4 * 4]);
    }
  }
  __syncthreads();
  // oproj + bias + residual + LN_ff -> s_fa (bf16), s_res
  if (tid < 160) {
    int r = tid >> 4, tx = tid & 15;
    float acc[5] = {};
    for (int d4 = 0; d4 < 20; ++d4) {
      float4 a = *reinterpret_cast<const float4*>(&s_at[r * 84 + d4 * 4]);
#pragma unroll
      for (int j = 0; j < 5; ++j) {
        float4 ww = *reinterpret_cast<const float4*>(&s_wo[(tx + 16 * j) * 84 + d4 * 4]);
        acc[j] += a.x * ww.x + a.y * ww.y + a.z * ww.z + a.w * ww.w;
      }
    }
    float val[5];
    float sm = 0.f, sq = 0.f;
#pragma unroll
    for (int j = 0; j < 5; ++j) {
      int c = tx + 16 * j;
      float v = acc[j] + bo[c] + s_x2[r * 84 + c];
      val[j] = v;
      s_res[r * 80 + c] = v;
      sm += v; sq += v * v;
    }
    for (int mm = 8; mm >= 1; mm >>= 1) {
      sm += __shfl_xor(sm, mm, 16);
      sq += __shfl_xor(sq, mm, 16);
    }
    float mu = sm * (1.f / DD);
    float ri = rsqrtf(sq * (1.f / DD) - mu * mu + EPSF);
#pragma unroll
    for (int j = 0; j < 5; ++j) {
      int c = tx + 16 * j;
      s_fa[r * 104 + c] = f2bf((val[j] - mu) * ri * ffg[c] + ffb[c]);
    }
  }
  __syncthreads();  // s_fa/s_res ready; s_at/s_wo dead
  {  // zero K-pad cols 80..95 of s_w1 (never overwritten by staging)
    int row = tid >> 1, half = tid & 1;
    uint4 z = make_uint4(0, 0, 0, 0);
    *reinterpret_cast<uint4*>(&s_w1[row * 104 + 80 + half * 8]) = z;
  }
  uint4 rw1[5], rw2[5];
#pragma unroll
  for (int k = 0; k < 5; ++k) {  // prefetch chunk 0
    int idx = tid + k * 256;
    int row1 = idx / 10, ch1 = idx % 10;
    rw1[k] = *reinterpret_cast<const uint4*>(&W1l[row1 * DD + ch1 * 8]);
  }
#pragma unroll
  for (int k = 0; k < 5; ++k) {
    int idx = tid + k * 256;
    int row2 = idx >> 4, ch2 = idx & 15;
    rw2[k] = *reinterpret_cast<const uint4*>(&W2l[row2 * FFND + ch2 * 8]);
  }
  f32x4 acc2[5] = {};
  for (int c = 0; c < 16; ++c) {
    int fc0 = c * 128;
    __syncthreads();  // prior chunk MFMA reads done
#pragma unroll
    for (int k = 0; k < 5; ++k) {
      int idx = tid + k * 256;
      int row1 = idx / 10, ch1 = idx % 10;
      *reinterpret_cast<uint4*>(&s_w1[row1 * 104 + ch1 * 8]) = rw1[k];
    }
#pragma unroll
    for (int k = 0; k < 5; ++k) {
      int idx = tid + k * 256;
      int row2 = idx >> 4, ch2 = idx & 15;
      *reinterpret_cast<uint4*>(&s_w2[row2 * 136 + ch2 * 8]) = rw2[k];
    }
    __syncthreads();
    if (c < 15) {  // issue next chunk loads; latency hides under MFMA
      int fn = fc0 + 128;
#pragma unroll
      for (int k = 0; k < 5; ++k) {
        int idx = tid + k * 256;
        int row1 = idx / 10, ch1 = idx % 10;
        rw1[k] = *reinterpret_cast<const uint4*>(&W1l[(fn + row1) * DD + ch1 * 8]);
      }
#pragma unroll
      for (int k = 0; k < 5; ++k) {
        int idx = tid + k * 256;
        int row2 = idx >> 4, ch2 = idx & 15;
        rw2[k] = *reinterpret_cast<const uint4*>(&W2l[row2 * FFND + fn + ch2 * 8]);
      }
    }
    // FFN1: wave w owns ffn cols [w*32, w*32+32) of this chunk
    f32x4 acc1[2] = {};
#pragma unroll
    for (int kk = 0; kk < 3; ++kk) {
      bf16x8 a = *reinterpret_cast<const bf16x8*>(&s_fa[m * 104 + kk * 32 + q * 8]);
#pragma unroll
      for (int ct2 = 0; ct2 < 2; ++ct2) {
        bf16x8 b = *reinterpret_cast<const bf16x8*>(
            &s_w1[(w * 32 + ct2 * 16 + m) * 104 + kk * 32 + q * 8]);
        acc1[ct2] = __builtin_amdgcn_mfma_f32_16x16x32_bf16(a, b, acc1[ct2], 0, 0, 0);
      }
    }
#pragma unroll
    for (int ct2 = 0; ct2 < 2; ++ct2) {
      float bias = b1l[fc0 + w * 32 + ct2 * 16 + m];
#pragma unroll
      for (int r = 0; r < 4; ++r)
        s_hw[(q * 4 + r) * 40 + ct2 * 16 + m] = f2bf(fmaxf(acc1[ct2][r] + bias, 0.f));
    }
    // FFN2 over this wave's 32-wide k-slice (wave-private s_h rows)
    bf16x8 a2 = *reinterpret_cast<const bf16x8*>(&s_hw[m * 40 + q * 8]);
#pragma unroll
    for (int ct = 0; ct < 5; ++ct) {
      bf16x8 b = *reinterpret_cast<const bf16x8*>(
          &s_w2[(ct * 16 + m) * 136 + w * 32 + q * 8]);
      acc2[ct] = __builtin_amdgcn_mfma_f32_16x16x32_bf16(a2, b, acc2[ct], 0, 0, 0);
    }
  }
  __syncthreads();  // MFMA reads of s_w1 done; s_red may overwrite
#pragma unroll
  for (int ct = 0; ct < 5; ++ct)
#pragma unroll
    for (int r = 0; r < 4; ++r)
      s_red[w * 1280 + (q * 4 + r) * 80 + ct * 16 + m] = acc2[ct][r];
  __syncthreads();
  for (int e = tid; e < 800; e += 256) {
    int row = e / 80, cc = e % 80;
    float v = s_red[row * 80 + cc] + s_red[1280 + row * 80 + cc] +
              s_red[2560 + row * 80 + cc] + s_red[3840 + row * 80 + cc];
    v += b2l[cc] + s_res[row * 80 + cc];
    s_val[e] = v;
  }
  __syncthreads();
  if (tid < 80) {
    int rr = tid >> 3, t8 = tid & 7;
    float sm = 0.f, sq = 0.f;
    for (int d = t8 * 10; d < t8 * 10 + 10; ++d) {
      float v = s_val[rr * 80 + d];
      sm += v; sq += v * v;
    }
    for (int mm = 4; mm >= 1; mm >>= 1) {
      sm += __shfl_xor(sm, mm, 8);
      sq += __shfl_xor(sq, mm, 8);
    }
    if (t8 == 0) {
      float mu = sm * (1.f / DD);
      s_mu2[rr] = mu;
      s_ri2[rr] = rsqrtf(sq * (1.f / DD) - mu * mu + EPSF);
    }
  }
  __syncthreads();
  for (int e = tid; e < 800; e += 256) {
    int row = e / 80, cc = e % 80;
    float xv = (s_val[e] - s_mu2[row]) * s_ri2[row] * ogl[cc] + obl[cc];
    x[(r0 + row) * DD + cc] = xv;
    s_val[e] = xv;                     // keep x rows in LDS for qkv(l+1)
  }
  // ---- fused QKV(l+1): row-local LN_in + GEMM over own 10 rows ----
  if (do_qkv) {
    __syncthreads();
    if (tid < 80) {
      int rr = tid >> 3, t8 = tid & 7;
      float sm = 0.f, sq = 0.f;
      for (int d = t8 * 10; d < t8 * 10 + 10; ++d) {
        float v = s_val[rr * 80 + d];
        sm += v; sq += v * v;
      }
      for (int mm = 4; mm >= 1; mm >>= 1) {
        sm += __shfl_xor(sm, mm, 8);
        sq += __shfl_xor(sq, mm, 8);
      }
      if (t8 == 0) {
        float mu = sm * (1.f / DD);
        s_mu2[rr] = mu;
        s_ri2[rr] = rsqrtf(sq * (1.f / DD) - mu * mu + EPSF);
      }
    }
    __syncthreads();
    for (int e = tid; e < 800; e += 256) {
      int row = e / 80, cc = e % 80;
      s_val[e] = (s_val[e] - s_mu2[row]) * s_ri2[row] * lng_n[cc] + lnb_n[cc];
    }
    __syncthreads();
    if (tid < 240) {
      const float* Wn;
      float bn;
      if (tid < 80) {
        Wn = Wq_n + tid * DD;
        bn = bq_n[tid];
      } else {
        Wn = Wkv_n + (tid - 80) * DD;
        bn = bkv_n[tid - 80];
      }
      float acc[10] = {};
      for (int d4 = 0; d4 < 20; ++d4) {
        float4 wv = *reinterpret_cast<const float4*>(&Wn[d4 * 4]);
#pragma unroll
        for (int r = 0; r < 10; ++r) {
          float4 sv = *reinterpret_cast<const float4*>(&s_val[r * 80 + d4 * 4]);
          acc[r] += sv.x * wv.x + sv.y * wv.y + sv.z * wv.z + sv.w * wv.w;
        }
      }
#pragma unroll
      for (int r = 0; r < 10; ++r)
        qkv[(r0 + r) * 240 + tid] = acc[r] + bn;
    }
  }
}

// ---------------- P: final projection + lengths tail ----------------
__global__ __launch_bounds__(256) void k_proj(
    const float* __restrict__ x, const float* __restrict__ Wp,
    const float* __restrict__ bp, const int* __restrict__ lengths,
    float* __restrict__ out) {
  __shared__ float s_a[64 * 84], s_w[64 * 84];
  int tid = threadIdx.x;
  int gr0 = blockIdx.x * 64;
  int c0 = blockIdx.y * 64;
  int b = gr0 / UU;
  int u0 = gr0 % UU;
  for (int k = 0; k < 5; ++k) {
    int idx = tid + k * 256;
    int row = idx / 20, c4 = idx % 20;
    *reinterpret_cast<float4*>(&s_a[row * 84 + c4 * 4]) =
        *reinterpret_cast<const float4*>(&x[(b * KK + RCL + u0 + row) * DD + c4 * 4]);
    *reinterpret_cast<float4*>(&s_w[row * 84 + c4 * 4]) =
        *reinterpret_cast<const float4*>(&Wp[(c0 + row) * DD + c4 * 4]);
  }
  __syncthreads();
  int ty = tid >> 4, tx = tid & 15;
  float acc[4][4] = {};
  for (int d4 = 0; d4 < 20; ++d4) {
    float4 a[4], w[4];
#pragma unroll
    for (int i2 = 0; i2 < 4; ++i2)
      a[i2] = *reinterpret_cast<const float4*>(&s_a[(4 * ty + i2) * 84 + d4 * 4]);
#pragma unroll
    for (int j = 0; j < 4; ++j)
      w[j] = *reinterpret_cast<const float4*>(&s_w[(tx + 16 * j) * 84 + d4 * 4]);
#pragma unroll
    for (int i2 = 0; i2 < 4; ++i2)
#pragma unroll
      for (int j = 0; j < 4; ++j)
        acc[i2][j] += a[i2].x * w[j].x + a[i2].y * w[j].y +
                      a[i2].z * w[j].z + a[i2].w * w[j].w;
  }
  for (int i2 = 0; i2 < 4; ++i2)
    for (int j = 0; j < 4; ++j) {
      int c = c0 + tx + 16 * j;
      out[(gr0 + 4 * ty + i2) * OUTD + c] = acc[i2][j] + bp[c];
    }
  if (blockIdx.x == 0 && blockIdx.y == 0 && tid < BB)
    out[BB * UU * OUTD + tid] = (float)lengths[tid];
}

extern "C" void kernel_launch(void* const* d_in, const int* in_sizes, int n_in,
                              void* d_out, int out_size, void* d_ws, size_t ws_size,
                              hipStream_t stream) {
  const float* mel   = (const float*)d_in[0];
  const float* lng   = (const float*)d_in[1];
  const float* lnb   = (const float*)d_in[2];
  const float* Wq    = (const float*)d_in[3];
  const float* bq    = (const float*)d_in[4];
  const float* Wkv   = (const float*)d_in[5];
  const float* bkv   = (const float*)d_in[6];
  const float* Wo    = (const float*)d_in[7];
  const float* bo    = (const float*)d_in[8];
  const float* ffg   = (const float*)d_in[9];
  const float* ffb   = (const float*)d_in[10];
  const float* W1    = (const float*)d_in[11];
  const float* b1    = (const float*)d_in[12];
  const float* W2    = (const float*)d_in[13];
  const float* b2    = (const float*)d_in[14];
  const float* og    = (const float*)d_in[15];
  const float* ob    = (const float*)d_in[16];
  const float* Wp    = (const float*)d_in[17];
  const float* bp    = (const float*)d_in[18];
  const int*   lens  = (const int*)d_in[19];
  float* out = (float*)d_out;

  float* ws = (float*)d_ws;
  float* x    = ws;                        // ROWS*DD
  float* qkv  = x + ROWS * DD;             // ROWS*240
  float* attn = qkv + ROWS * 240;          // ROWS*DD
  unsigned short* w1bf = (unsigned short*)(attn + ROWS * DD);  // LL*FFND*DD bf16
  unsigned short* w2bf = w1bf + LL * FFND * DD;                // LL*FFND*DD bf16

  k_gather<<<(ROWS * DD + 255) / 256, 256, 0, stream>>>(mel, x);
  k_cvt<<<(2 * (LL * FFND * DD) / 4 + 255) / 256, 256, 0, stream>>>(W1, W2, w1bf, w2bf);
  k_qkv<<<dim3(ROWS / 32, 3), 256, 0, stream>>>(
      x, qkv, Wq, bq, Wkv, bkv, lng, lnb);

  for (int l = 0; l < LL; ++l) {
    int ln = (l < LL - 1) ? l + 1 : l;  // next-layer params (unused when l==11)
    k_attn<<<dim3(NSEG, HH, BB), 256, 0, stream>>>(qkv, attn, lens);
    k_fused<<<ROWS / 10, 256, 0, stream>>>(
        attn, x, qkv,
        Wo + l * DD * DD, bo + l * DD,
        ffg + l * DD, ffb + l * DD,
        w1bf + l * FFND * DD, b1 + l * FFND,
        w2bf + l * FFND * DD, b2 + l * DD,
        og + l * DD, ob + l * DD,
        lng + ln * DD, lnb + ln * DD,
        Wq + ln * DD * DD, bq + ln * DD,
        Wkv + ln * 2 * DD * DD, bkv + ln * 2 * DD,
        (l < LL - 1) ? 1 : 0);
  }

  k_proj<<<dim3(BB * UU / 64, OUTD / 64), 256, 0, stream>>>(x, Wp, bp, lens, out);
}